// Round 7
// baseline (710.029 us; speedup 1.0000x reference)
//
#include <hip/hip_runtime.h>

#define N_NODES 50000
#define MPAD    50176
#define N_EDGES 800000
#define IN_DIM 128
#define HID 256
#define OUT_DIM 64
#define N_CONV 4
#define KCAT 1152   // 128 + 4*256

typedef __bf16 bf16;
typedef __attribute__((ext_vector_type(8))) __bf16 bf16x8;
typedef __attribute__((ext_vector_type(4))) float f32x4;
typedef unsigned short ushort_t;

__device__ __forceinline__ unsigned short f2b(float f){
  unsigned u = __float_as_uint(f);
  u += 0x7fffu + ((u >> 16) & 1u);
  return (unsigned short)(u >> 16);
}
__device__ __forceinline__ float b2f_lo(unsigned v){ return __uint_as_float(v << 16); }
__device__ __forceinline__ float b2f_hi(unsigned v){ return __uint_as_float(v & 0xffff0000u); }

__device__ __forceinline__ void stage16(const void* g, void* l){
  __builtin_amdgcn_global_load_lds((const __attribute__((address_space(1))) unsigned int*)g,
                                   (__attribute__((address_space(3))) unsigned int*)l, 16, 0, 0);
}

// ---------------- CSR build ----------------
__global__ void k_count(const int* __restrict__ dst, int* __restrict__ cnt, int ne){
  int e = blockIdx.x*blockDim.x + threadIdx.x;
  if (e < ne) atomicAdd(&cnt[dst[e]], 1);
}

__global__ void k_scan1(const int* __restrict__ cnt, int* __restrict__ scanned,
                        int* __restrict__ bsum, int n){
  int i = blockIdx.x*256 + threadIdx.x;
  int v = (i < n) ? cnt[i] : 0;
  int lane = threadIdx.x & 63;
  #pragma unroll
  for (int off = 1; off < 64; off <<= 1){
    int t = __shfl_up(v, off, 64);
    if (lane >= off) v += t;
  }
  __shared__ int wsum[4];
  int wv = threadIdx.x >> 6;
  if (lane == 63) wsum[wv] = v;
  __syncthreads();
  if (threadIdx.x == 0){
    int s = 0;
    #pragma unroll
    for (int k = 0; k < 4; ++k){ int t = wsum[k]; wsum[k] = s; s += t; }
    bsum[blockIdx.x] = s;
  }
  __syncthreads();
  v += wsum[wv];
  if (i < n) scanned[i] = v;
}

__global__ void k_scan2(int* __restrict__ bsum, int nb){
  __shared__ int sd[256];
  int i = threadIdx.x;
  sd[i] = (i < nb) ? bsum[i] : 0;
  __syncthreads();
  #pragma unroll
  for (int off = 1; off < 256; off <<= 1){
    int t = (i >= off) ? sd[i-off] : 0;
    __syncthreads();
    sd[i] += t;
    __syncthreads();
  }
  if (i < nb) bsum[i] = sd[i];
}

__global__ void k_scan3(const int* __restrict__ scanned, const int* __restrict__ bsum,
                        const int* __restrict__ cnt, int* __restrict__ row_ptr,
                        int* __restrict__ cursor, int n){
  int i = blockIdx.x*256 + threadIdx.x;
  if (i < n){
    int off = (blockIdx.x > 0) ? bsum[blockIdx.x-1] : 0;
    int inc = scanned[i] + off;
    row_ptr[i+1] = inc;
    cursor[i] = inc - cnt[i];
  }
  if (i == 0) row_ptr[0] = 0;
}

__global__ void k_fill(const int* __restrict__ src, const int* __restrict__ dst,
                       int* __restrict__ cursor, int* __restrict__ esrc, int ne){
  int e = blockIdx.x*blockDim.x + threadIdx.x;
  if (e < ne){
    int p = atomicAdd(&cursor[dst[e]], 1);
    esrc[p] = src[e];
  }
}

// ---------------- zero helper: 3 byte-ranges in one dispatch ----------------
__global__ void k_zero(char* p0, int n0, char* p1, int n1, char* p2, int n2){
  int i = (blockIdx.x*blockDim.x + threadIdx.x) * 16;
  if (i < n0) *(uint4*)(p0 + i) = make_uint4(0,0,0,0);
  i -= n0;
  if (i >= 0 && i < n1) *(uint4*)(p1 + i) = make_uint4(0,0,0,0);
  i -= n1;
  if (i >= 0 && i < n2) *(uint4*)(p2 + i) = make_uint4(0,0,0,0);
}

// ---------------- aggregation from xcat slice (bf16, fp32 accum, 8x MLP) ----------------
template<int D>
__global__ void k_agg(const ushort_t* __restrict__ x, const int* __restrict__ rp,
                      const int* __restrict__ es, ushort_t* __restrict__ agg, int n){
  int gw = (int)((blockIdx.x*(size_t)blockDim.x + threadIdx.x) >> 6);
  int lane = threadIdx.x & 63;
  if (gw >= n) return;
  if (D == 256){
    const uint2* xp = (const uint2*)x; const int S = KCAT/4;
    uint2 v = xp[(size_t)gw*S + lane];
    float a0=b2f_lo(v.x), a1=b2f_hi(v.x), a2=b2f_lo(v.y), a3=b2f_hi(v.y);
    float c0=0.f, c1=0.f, c2=0.f, c3=0.f;
    int e = rp[gw], e1 = rp[gw+1];
    for (; e + 8 <= e1; e += 8){
      uint2 w[8];
      #pragma unroll
      for (int u = 0; u < 8; ++u) w[u] = xp[(size_t)es[e+u]*S + lane];
      #pragma unroll
      for (int u = 0; u < 8; u += 2){
        a0 += b2f_lo(w[u].x);   a1 += b2f_hi(w[u].x);   a2 += b2f_lo(w[u].y);   a3 += b2f_hi(w[u].y);
        c0 += b2f_lo(w[u+1].x); c1 += b2f_hi(w[u+1].x); c2 += b2f_lo(w[u+1].y); c3 += b2f_hi(w[u+1].y);
      }
    }
    for (; e + 2 <= e1; e += 2){
      uint2 w0 = xp[(size_t)es[e]*S + lane];
      uint2 w1 = xp[(size_t)es[e+1]*S + lane];
      a0 += b2f_lo(w0.x); a1 += b2f_hi(w0.x); a2 += b2f_lo(w0.y); a3 += b2f_hi(w0.y);
      c0 += b2f_lo(w1.x); c1 += b2f_hi(w1.x); c2 += b2f_lo(w1.y); c3 += b2f_hi(w1.y);
    }
    if (e < e1){
      uint2 w0 = xp[(size_t)es[e]*S + lane];
      a0 += b2f_lo(w0.x); a1 += b2f_hi(w0.x); a2 += b2f_lo(w0.y); a3 += b2f_hi(w0.y);
    }
    a0 += c0; a1 += c1; a2 += c2; a3 += c3;
    unsigned o0 = (unsigned)f2b(a0) | ((unsigned)f2b(a1) << 16);
    unsigned o1 = (unsigned)f2b(a2) | ((unsigned)f2b(a3) << 16);
    *(uint2*)(agg + (size_t)gw*256 + lane*4) = make_uint2(o0, o1);
  } else {
    const unsigned* xp = (const unsigned*)x; const int S = KCAT/2;
    unsigned v = xp[(size_t)gw*S + lane];
    float a0 = b2f_lo(v), a1 = b2f_hi(v);
    float c0 = 0.f, c1 = 0.f;
    int e = rp[gw], e1 = rp[gw+1];
    for (; e + 8 <= e1; e += 8){
      unsigned w[8];
      #pragma unroll
      for (int u = 0; u < 8; ++u) w[u] = xp[(size_t)es[e+u]*S + lane];
      #pragma unroll
      for (int u = 0; u < 8; u += 2){
        a0 += b2f_lo(w[u]);   a1 += b2f_hi(w[u]);
        c0 += b2f_lo(w[u+1]); c1 += b2f_hi(w[u+1]);
      }
    }
    for (; e + 2 <= e1; e += 2){
      unsigned w0 = xp[(size_t)es[e]*S + lane];
      unsigned w1 = xp[(size_t)es[e+1]*S + lane];
      a0 += b2f_lo(w0); a1 += b2f_hi(w0);
      c0 += b2f_lo(w1); c1 += b2f_hi(w1);
    }
    if (e < e1){
      unsigned w0 = xp[(size_t)es[e]*S + lane];
      a0 += b2f_lo(w0); a1 += b2f_hi(w0);
    }
    a0 += c0; a1 += c1;
    unsigned o = (unsigned)f2b(a0) | ((unsigned)f2b(a1) << 16);
    *(unsigned*)(agg + (size_t)gw*128 + lane*2) = o;
  }
}

// ---------------- BN+ReLU (bf16 in, bf16 out, inline stats, strided output) ----------------
__global__ void k_bnrelu(const ushort_t* __restrict__ t, const float* __restrict__ sums,
                         const float* __restrict__ g, const float* __restrict__ b,
                         ushort_t* __restrict__ o, int ostride, int M, float invM){
  int idx = blockIdx.x*blockDim.x + threadIdx.x;
  if (idx >= M*(HID/8)) return;
  int row = idx >> 5, cg = (idx & 31) * 8;
  uint4 v = *(const uint4*)(t + (size_t)row*HID + cg);
  unsigned wv[4] = {v.x, v.y, v.z, v.w};
  unsigned ov[4];
  #pragma unroll
  for (int p = 0; p < 4; ++p){
    int c0 = cg + 2*p, c1 = c0 + 1;
    float m0 = sums[c0]*invM, m1 = sums[c1]*invM;
    float r0 = rsqrtf(sums[HID+c0]*invM - m0*m0 + 1e-5f);
    float r1 = rsqrtf(sums[HID+c1]*invM - m1*m1 + 1e-5f);
    float y0 = (b2f_lo(wv[p]) - m0)*r0*g[c0] + b[c0];
    float y1 = (b2f_hi(wv[p]) - m1)*r1*g[c1] + b[c1];
    y0 = y0 > 0.f ? y0 : 0.f; y1 = y1 > 0.f ? y1 : 0.f;
    ov[p] = (unsigned)f2b(y0) | ((unsigned)f2b(y1) << 16);
  }
  *(uint4*)(o + (size_t)row*ostride + cg) = make_uint4(ov[0], ov[1], ov[2], ov[3]);
}

// ---------------- h fp32 -> bf16 into xcat col 0..127 ----------------
__global__ void k_f2b(const float* __restrict__ in, ushort_t* __restrict__ xcat, int n8){
  int idx = blockIdx.x*blockDim.x + threadIdx.x;
  if (idx >= n8) return;
  int row = idx >> 4, cg = (idx & 15) * 8;
  float4 a = *(const float4*)(in + (size_t)row*IN_DIM + cg);
  float4 c = *(const float4*)(in + (size_t)row*IN_DIM + cg + 4);
  unsigned o0 = (unsigned)f2b(a.x) | ((unsigned)f2b(a.y) << 16);
  unsigned o1 = (unsigned)f2b(a.z) | ((unsigned)f2b(a.w) << 16);
  unsigned o2 = (unsigned)f2b(c.x) | ((unsigned)f2b(c.y) << 16);
  unsigned o3 = (unsigned)f2b(c.z) | ((unsigned)f2b(c.w) << 16);
  *(uint4*)(xcat + (size_t)row*KCAT + cg) = make_uint4(o0, o1, o2, o3);
}

// ---------------- weight transpose + convert (+ fused bias fold) ----------------
__global__ void k_wprep(const float* __restrict__ c0W1, const float* __restrict__ cW1,
                        const float* __restrict__ cW2, const float* __restrict__ p0W,
                        const float* __restrict__ pW,
                        const float* __restrict__ p0b, const float* __restrict__ pb,
                        ushort_t* __restrict__ wb, ushort_t* __restrict__ whead,
                        float* __restrict__ ball){
  int m = blockIdx.y;
  if (m == 13){
    if (blockIdx.x == 0 && threadIdx.x < OUT_DIM){
      int c = threadIdx.x;
      float v = p0b[c];
      #pragma unroll
      for (int i = 0; i < N_CONV; ++i) v += pb[i*OUT_DIM + c];
      ball[c] = v;
    }
    return;
  }
  const float* src; int R, C; ushort_t* dst; int dstride, dcol;
  if (m == 0){       src = c0W1;              R = 128; C = 256; dst = wb;                       dstride = 128;  dcol = 0; }
  else if (m <= 3){  src = cW1 + (m-1)*65536; R = 256; C = 256; dst = wb + 32768 + (m-1)*65536; dstride = 256;  dcol = 0; }
  else if (m <= 7){  src = cW2 + (m-4)*65536; R = 256; C = 256; dst = wb + 229376 + (m-4)*65536;dstride = 256;  dcol = 0; }
  else if (m == 8){  src = p0W;               R = 128; C = 64;  dst = whead;                    dstride = KCAT; dcol = 0; }
  else {             src = pW + (m-9)*16384;  R = 256; C = 64;  dst = whead;                    dstride = KCAT; dcol = 128 + (m-9)*256; }
  int tx = R/64, tiles = tx * (C/64);
  int t = blockIdx.x;
  if (t >= tiles) return;
  int sr0 = (t % tx)*64, sc0 = (t / tx)*64;
  __shared__ float ld[64][65];
  int c = threadIdx.x & 63, rq = threadIdx.x >> 6;
  #pragma unroll
  for (int i = 0; i < 16; ++i){
    int rr = i*4 + rq;
    ld[rr][c] = src[(size_t)(sr0+rr)*C + sc0 + c];
  }
  __syncthreads();
  #pragma unroll
  for (int i = 0; i < 16; ++i){
    int rr = i*4 + rq;
    dst[(size_t)(sc0+rr)*dstride + dcol + sr0 + c] = f2b(ld[c][rr]);
  }
}

// ---------------- MFMA GEMM: C[M,N] = A[M,K](bf16) @ BT[N,K](bf16)^T ----------------
// A staged in LDS (global_load_lds or fused-BN reg-staging); B read straight from
// global (L2-resident weight) into register fragments, double-buffered one K-tile ahead.
// MODE 0: round acc->bf16, fused column stats from rounded values, bf16 C (all rows incl pad)
// MODE 1: fp32 C + bias[col], masked row<M
// MODE 2: like MODE 0, but A reg-staged with fused BN(asums)+ReLU affine and pad-row zeroing
template<int BM, int BN, int MODE>
__global__ __launch_bounds__((BM/64)*(BN/64)*64)
void k_mgemm(const bf16* __restrict__ A, const bf16* __restrict__ BT,
             void* __restrict__ Cv, const float* __restrict__ bias,
             float* __restrict__ sums, const float* __restrict__ asums,
             const float* __restrict__ ag, const float* __restrict__ ab,
             int M, int N, int K, float invM)
{
  constexpr int NW  = (BM/64)*(BN/64);
  constexpr int WNT = BN/64;
  constexpr int ACH = BM/16;
  __shared__ __align__(16) bf16 As[2*BM*32];
  __shared__ float sAf[MODE==2?256:1];
  __shared__ float tAf[MODE==2?256:1];
  const int tid = threadIdx.x;
  const int wid = tid >> 6, l = tid & 63;
  const int wm = wid / WNT, wn = wid % WNT;
  const int m0 = blockIdx.y * BM, n0 = blockIdx.x * BN;
  const int r = l & 15, q = l >> 4;
  const int fragByte = ((q ^ ((r >> 1) & 3)) << 4);
  const int wrow = l >> 2;
  const int wk = (((l & 3) ^ ((l >> 3) & 3)) << 3);

  if constexpr (MODE == 2){
    if (tid < 256){
      float m = asums[tid] * invM;
      float var = asums[256 + tid] * invM - m*m;
      float s = rsqrtf(var + 1e-5f) * ag[tid];
      sAf[tid] = s;
      tAf[tid] = ab[tid] - m*s;
    }
    __syncthreads();
  }

  auto STAGE_A = [&](int buf, int k0){
    #pragma unroll
    for (int c = 0; c < ACH/NW; ++c){
      int ch = wid + c*NW;
      if constexpr (MODE == 2){
        int grow = m0 + ch*16 + wrow;
        uint4 raw = *(const uint4*)(A + (size_t)grow*K + (k0 + wk));
        int kc = k0 + wk;
        unsigned rv[4] = {raw.x, raw.y, raw.z, raw.w};
        unsigned ov[4];
        #pragma unroll
        for (int p = 0; p < 4; ++p){
          int c0 = kc + 2*p, c1 = c0 + 1;
          float y0 = fmaf(b2f_lo(rv[p]), sAf[c0], tAf[c0]);
          float y1 = fmaf(b2f_hi(rv[p]), sAf[c1], tAf[c1]);
          y0 = y0 > 0.f ? y0 : 0.f; y1 = y1 > 0.f ? y1 : 0.f;
          ov[p] = (unsigned)f2b(y0) | ((unsigned)f2b(y1) << 16);
        }
        if (grow >= M){ ov[0]=0; ov[1]=0; ov[2]=0; ov[3]=0; }
        *(uint4*)((char*)As + buf*(BM*64) + ch*1024 + l*16) = make_uint4(ov[0],ov[1],ov[2],ov[3]);
      } else {
        const bf16* g = A + (size_t)(m0 + ch*16 + wrow)*K + (k0 + wk);
        stage16(g, (char*)As + buf*(BM*64) + ch*1024);
      }
    }
  };

  // B fragment loader: lane (r,q) takes col n0+wn*64+nf*16+r, k = k0+q*8 .. +7
  const bf16* Bbase = BT + (size_t)(n0 + wn*64 + r)*K + q*8;
  auto LOADB = [&](bf16x8* d, int k0){
    #pragma unroll
    for (int nf = 0; nf < 4; ++nf)
      d[nf] = *(const bf16x8*)(Bbase + (size_t)nf*16*K + k0);
  };

  f32x4 acc[4][4] = {};
  const int nt = K >> 5;
  bf16x8 bcur[4], bnxt[4];
  STAGE_A(0, 0);
  LOADB(bcur, 0);
  for (int t = 0; t < nt; ++t){
    int cur = t & 1;
    __syncthreads();                       // As[cur] staged; prev-tile LDS reads done
    if (t + 1 < nt){
      STAGE_A(cur ^ 1, (t + 1) << 5);
      LOADB(bnxt, (t + 1) << 5);
    }
    bf16x8 af[4];
    #pragma unroll
    for (int mf = 0; mf < 4; ++mf)
      af[mf] = *(const bf16x8*)((const char*)As + cur*(BM*64) + (wm*64 + mf*16 + r)*64 + fragByte);
    #pragma unroll
    for (int mf = 0; mf < 4; ++mf)
      #pragma unroll
      for (int nf = 0; nf < 4; ++nf)
        acc[mf][nf] = __builtin_amdgcn_mfma_f32_16x16x32_bf16(af[mf], bcur[nf], acc[mf][nf], 0, 0, 0);
    #pragma unroll
    for (int nf = 0; nf < 4; ++nf) bcur[nf] = bnxt[nf];
  }

  if (MODE == 0 || MODE == 2){
    ushort_t* Cb = (ushort_t*)Cv;
    float s1[4] = {0.f,0.f,0.f,0.f}, s2[4] = {0.f,0.f,0.f,0.f};
    #pragma unroll
    for (int mf = 0; mf < 4; ++mf){
      #pragma unroll
      for (int j = 0; j < 4; ++j){
        int row = m0 + wm*64 + mf*16 + q*4 + j;
        #pragma unroll
        for (int nf = 0; nf < 4; ++nf){
          unsigned short us = f2b(acc[mf][nf][j]);
          float vr = __uint_as_float((unsigned)us << 16);
          s1[nf] += vr; s2[nf] = fmaf(vr, vr, s2[nf]);
          Cb[(size_t)row*N + n0 + wn*64 + nf*16 + r] = us;
        }
      }
    }
    #pragma unroll
    for (int nf = 0; nf < 4; ++nf){
      float a = s1[nf], c = s2[nf];
      a += __shfl_xor(a, 16, 64); a += __shfl_xor(a, 32, 64);
      c += __shfl_xor(c, 16, 64); c += __shfl_xor(c, 32, 64);
      if (q == 0){
        int col = n0 + wn*64 + nf*16 + r;
        atomicAdd(&sums[col], a);
        atomicAdd(&sums[256 + col], c);
      }
    }
  } else {
    float* C = (float*)Cv;
    #pragma unroll
    for (int mf = 0; mf < 4; ++mf){
      #pragma unroll
      for (int j = 0; j < 4; ++j){
        int row = m0 + wm*64 + mf*16 + q*4 + j;
        if (row >= M) continue;
        #pragma unroll
        for (int nf = 0; nf < 4; ++nf){
          int col = n0 + wn*64 + nf*16 + r;
          C[(size_t)row*N + col] = acc[mf][nf][j] + bias[col];
        }
      }
    }
  }
}

extern "C" void kernel_launch(void* const* d_in, const int* in_sizes, int n_in,
                              void* d_out, int out_size, void* d_ws, size_t ws_size,
                              hipStream_t stream){
  const float* h    = (const float*)d_in[0];
  const float* c0W1 = (const float*)d_in[1];
  const float* cW1  = (const float*)d_in[2];
  const float* cW2  = (const float*)d_in[3];
  const float* bn1g = (const float*)d_in[4];
  const float* bn1b = (const float*)d_in[5];
  const float* bn2g = (const float*)d_in[6];
  const float* bn2b = (const float*)d_in[7];
  const float* p0W  = (const float*)d_in[8];
  const float* p0b  = (const float*)d_in[9];
  const float* pW   = (const float*)d_in[10];
  const float* pb   = (const float*)d_in[11];
  const int* src    = (const int*)d_in[12];
  const int* dst    = (const int*)d_in[13];
  float* out = (float*)d_out;

  char* w = (char*)d_ws;
  auto alloc = [&](size_t bytes)->char*{ char* p = w; w += (bytes + 255) & ~(size_t)255; return p; };
  ushort_t* xcat = (ushort_t*)alloc((size_t)MPAD*KCAT*2);
  ushort_t* aggb = (ushort_t*)alloc((size_t)MPAD*HID*2);
  ushort_t* tt   = (ushort_t*)alloc((size_t)MPAD*HID*2);
  ushort_t* wb   = (ushort_t*)alloc((size_t)491520*2);
  ushort_t* whead= (ushort_t*)alloc((size_t)OUT_DIM*KCAT*2);
  int* row_ptr   = (int*)alloc((N_NODES+1)*4);
  int* cursor    = (int*)alloc(N_NODES*4);
  int* counts    = (int*)alloc(N_NODES*4);
  int* esrc      = (int*)alloc(N_EDGES*4);
  int* scanned   = (int*)alloc(N_NODES*4);
  int* bsum      = (int*)alloc(256*4);
  float* sums8   = (float*)alloc(8*512*4);
  float* ball    = (float*)alloc(OUT_DIM*4);

  // pad-row zeroing (128-wide + 256-wide views) + sums, one dispatch
  {
    const int PADR = MPAD - N_NODES;
    int n0 = PADR*IN_DIM*2, n1 = PADR*HID*2, n2 = 8*512*4;
    int chunks = (n0 + n1 + n2) / 16;
    k_zero<<<(chunks + 255)/256, 256, 0, stream>>>(
        (char*)(aggb + (size_t)N_NODES*IN_DIM), n0,
        (char*)(aggb + (size_t)N_NODES*HID), n1,
        (char*)sums8, n2);
  }

  // ---- CSR build (by dst) ----
  const int NB = (N_NODES + 255) / 256;
  hipMemsetAsync(counts, 0, N_NODES*4, stream);
  k_count<<<(N_EDGES+255)/256, 256, 0, stream>>>(dst, counts, N_EDGES);
  k_scan1<<<NB, 256, 0, stream>>>(counts, scanned, bsum, N_NODES);
  k_scan2<<<1, 256, 0, stream>>>(bsum, NB);
  k_scan3<<<NB, 256, 0, stream>>>(scanned, bsum, counts, row_ptr, cursor, N_NODES);
  k_fill<<<(N_EDGES+255)/256, 256, 0, stream>>>(src, dst, cursor, esrc, N_EDGES);

  // ---- weight prep (+bias fold) + h->xcat ----
  k_wprep<<<dim3(16, 14), 256, 0, stream>>>(c0W1, cW1, cW2, p0W, pW, p0b, pb, wb, whead, ball);
  k_f2b<<<(N_NODES*16 + 255)/256, 256, 0, stream>>>(h, xcat, N_NODES*16);

  const float invM = 1.0f / (float)N_NODES;
  for (int i = 0; i < N_CONV; ++i){
    int K1 = (i == 0) ? IN_DIM : HID;
    const ushort_t* xin = (i == 0) ? xcat : (xcat + 128 + (size_t)(i-1)*HID);
    if (i == 0)
      k_agg<IN_DIM><<<(N_NODES*64+255)/256, 256, 0, stream>>>(xin, row_ptr, esrc, aggb, N_NODES);
    else
      k_agg<HID><<<(N_NODES*64+255)/256, 256, 0, stream>>>(xin, row_ptr, esrc, aggb, N_NODES);

    float* sums1 = sums8 + (size_t)(2*i)*512;
    float* sums2 = sums8 + (size_t)(2*i+1)*512;

    // GEMM1: tt = aggb @ W1  (+ fused stats of rounded output)
    const ushort_t* W1T = (i == 0) ? wb : (wb + 32768 + (size_t)(i-1)*65536);
    k_mgemm<64, 256, 0><<<dim3(1, MPAD/64), 256, 0, stream>>>(
        (const bf16*)aggb, (const bf16*)W1T, tt, nullptr, sums1,
        nullptr, nullptr, nullptr, N_NODES, HID, K1, invM);

    // GEMM2: aggb = relu(bn1(tt)) @ W2  (BN1+ReLU fused into A-staging; fused stats)
    const ushort_t* W2T = wb + 229376 + (size_t)i*65536;
    k_mgemm<64, 256, 2><<<dim3(1, MPAD/64), 256, 0, stream>>>(
        (const bf16*)tt, (const bf16*)W2T, aggb, nullptr, sums2,
        sums1, bn1g + i*HID, bn1b + i*HID, N_NODES, HID, HID, invM);

    // BN2+ReLU -> xcat slice
    k_bnrelu<<<(N_NODES*32 + 255)/256, 256, 0, stream>>>(
        aggb, sums2, bn2g + i*HID, bn2b + i*HID, xcat + 128 + (size_t)i*HID, KCAT, N_NODES, invM);
  }

  // ---- consolidated jumping-knowledge head GEMM: out = xcat @ whead^T + ball ----
  k_mgemm<128, 64, 1><<<dim3(1, MPAD/128), 128, 0, stream>>>(
      (const bf16*)xcat, (const bf16*)whead, out, ball, nullptr,
      nullptr, nullptr, nullptr, N_NODES, OUT_DIM, KCAT, invM);
}

// Round 8
// 686.242 us; speedup vs baseline: 1.0347x; 1.0347x over previous
//
#include <hip/hip_runtime.h>

#define N_NODES 50000
#define MPAD    50176
#define N_EDGES 800000
#define IN_DIM 128
#define HID 256
#define OUT_DIM 64
#define N_CONV 4
#define KCAT 1152   // 128 + 4*256

typedef __bf16 bf16;
typedef __attribute__((ext_vector_type(8))) __bf16 bf16x8;
typedef __attribute__((ext_vector_type(4))) float f32x4;
typedef unsigned short ushort_t;

__device__ __forceinline__ unsigned short f2b(float f){
  unsigned u = __float_as_uint(f);
  u += 0x7fffu + ((u >> 16) & 1u);
  return (unsigned short)(u >> 16);
}
__device__ __forceinline__ float b2f_lo(unsigned v){ return __uint_as_float(v << 16); }
__device__ __forceinline__ float b2f_hi(unsigned v){ return __uint_as_float(v & 0xffff0000u); }

__device__ __forceinline__ void stage16(const void* g, void* l){
  __builtin_amdgcn_global_load_lds((const __attribute__((address_space(1))) unsigned int*)g,
                                   (__attribute__((address_space(3))) unsigned int*)l, 16, 0, 0);
}

// ---------------- CSR build ----------------
__global__ void k_count(const int* __restrict__ dst, int* __restrict__ cnt, int ne){
  int e = blockIdx.x*blockDim.x + threadIdx.x;
  if (e < ne) atomicAdd(&cnt[dst[e]], 1);
}

__global__ void k_scan1(const int* __restrict__ cnt, int* __restrict__ scanned,
                        int* __restrict__ bsum, int n){
  int i = blockIdx.x*256 + threadIdx.x;
  int v = (i < n) ? cnt[i] : 0;
  int lane = threadIdx.x & 63;
  #pragma unroll
  for (int off = 1; off < 64; off <<= 1){
    int t = __shfl_up(v, off, 64);
    if (lane >= off) v += t;
  }
  __shared__ int wsum[4];
  int wv = threadIdx.x >> 6;
  if (lane == 63) wsum[wv] = v;
  __syncthreads();
  if (threadIdx.x == 0){
    int s = 0;
    #pragma unroll
    for (int k = 0; k < 4; ++k){ int t = wsum[k]; wsum[k] = s; s += t; }
    bsum[blockIdx.x] = s;
  }
  __syncthreads();
  v += wsum[wv];
  if (i < n) scanned[i] = v;
}

__global__ void k_scan2(int* __restrict__ bsum, int nb){
  __shared__ int sd[256];
  int i = threadIdx.x;
  sd[i] = (i < nb) ? bsum[i] : 0;
  __syncthreads();
  #pragma unroll
  for (int off = 1; off < 256; off <<= 1){
    int t = (i >= off) ? sd[i-off] : 0;
    __syncthreads();
    sd[i] += t;
    __syncthreads();
  }
  if (i < nb) bsum[i] = sd[i];
}

__global__ void k_scan3(const int* __restrict__ scanned, const int* __restrict__ bsum,
                        const int* __restrict__ cnt, int* __restrict__ row_ptr,
                        int* __restrict__ cursor, int n){
  int i = blockIdx.x*256 + threadIdx.x;
  if (i < n){
    int off = (blockIdx.x > 0) ? bsum[blockIdx.x-1] : 0;
    int inc = scanned[i] + off;
    row_ptr[i+1] = inc;
    cursor[i] = inc - cnt[i];
  }
  if (i == 0) row_ptr[0] = 0;
}

__global__ void k_fill(const int* __restrict__ src, const int* __restrict__ dst,
                       int* __restrict__ cursor, int* __restrict__ esrc, int ne){
  int e = blockIdx.x*blockDim.x + threadIdx.x;
  if (e < ne){
    int p = atomicAdd(&cursor[dst[e]], 1);
    esrc[p] = src[e];
  }
}

// ---------------- zero helper: 4 byte-ranges in one dispatch ----------------
__global__ void k_zero(char* p0, int n0, char* p1, int n1, char* p2, int n2, char* p3, int n3){
  int i = (blockIdx.x*blockDim.x + threadIdx.x) * 16;
  if (i < n0) *(uint4*)(p0 + i) = make_uint4(0,0,0,0);
  i -= n0;
  if (i >= 0 && i < n1) *(uint4*)(p1 + i) = make_uint4(0,0,0,0);
  i -= n1;
  if (i >= 0 && i < n2) *(uint4*)(p2 + i) = make_uint4(0,0,0,0);
  i -= n2;
  if (i >= 0 && i < n3) *(uint4*)(p3 + i) = make_uint4(0,0,0,0);
}

// ---------------- layer-0 aggregation (bf16 from xcat h-slice, fp32 accum) ----------------
__global__ void k_agg0(const ushort_t* __restrict__ x, const int* __restrict__ rp,
                       const int* __restrict__ es, ushort_t* __restrict__ agg, int n){
  int gw = (int)((blockIdx.x*(size_t)blockDim.x + threadIdx.x) >> 6);
  int lane = threadIdx.x & 63;
  if (gw >= n) return;
  const unsigned* xp = (const unsigned*)x; const int S = KCAT/2;
  unsigned v = xp[(size_t)gw*S + lane];
  float a0 = b2f_lo(v), a1 = b2f_hi(v);
  float c0 = 0.f, c1 = 0.f;
  int e = rp[gw], e1 = rp[gw+1];
  for (; e + 8 <= e1; e += 8){
    unsigned w[8];
    #pragma unroll
    for (int u = 0; u < 8; ++u) w[u] = xp[(size_t)es[e+u]*S + lane];
    #pragma unroll
    for (int u = 0; u < 8; u += 2){
      a0 += b2f_lo(w[u]);   a1 += b2f_hi(w[u]);
      c0 += b2f_lo(w[u+1]); c1 += b2f_hi(w[u+1]);
    }
  }
  for (; e + 2 <= e1; e += 2){
    unsigned w0 = xp[(size_t)es[e]*S + lane];
    unsigned w1 = xp[(size_t)es[e+1]*S + lane];
    a0 += b2f_lo(w0); a1 += b2f_hi(w0);
    c0 += b2f_lo(w1); c1 += b2f_hi(w1);
  }
  if (e < e1){
    unsigned w0 = xp[(size_t)es[e]*S + lane];
    a0 += b2f_lo(w0); a1 += b2f_hi(w0);
  }
  a0 += c0; a1 += c1;
  unsigned o = (unsigned)f2b(a0) | ((unsigned)f2b(a1) << 16);
  *(unsigned*)(agg + (size_t)gw*128 + lane*2) = o;
}

// ---------------- fused BN2+ReLU + aggregation (layers 1..3) ----------------
// x: raw GEMM2 output [n][256] bf16 (contiguous). Applies y = relu(x*sc+sh) per column
// on the fly; writes transformed self-row to xcat slice (stride KCAT) and the
// aggregated row (bf16) to agg (stride 256).
__global__ void k_aggbn(const ushort_t* __restrict__ x, const int* __restrict__ rp,
                        const int* __restrict__ es, ushort_t* __restrict__ agg,
                        ushort_t* __restrict__ xc,
                        const float* __restrict__ sums, const float* __restrict__ g,
                        const float* __restrict__ b, float invM, int n){
  int gw = (int)((blockIdx.x*(size_t)blockDim.x + threadIdx.x) >> 6);
  int lane = threadIdx.x & 63;
  if (gw >= n) return;
  float sc[4], sh[4];
  #pragma unroll
  for (int j = 0; j < 4; ++j){
    int c = lane*4 + j;
    float m = sums[c]*invM;
    float var = sums[256 + c]*invM - m*m;
    float r = rsqrtf(var + 1e-5f);
    sc[j] = r * g[c];
    sh[j] = b[c] - m*sc[j];
  }
  const uint2* xp = (const uint2*)x;  // row stride 64 uint2
  uint2 v = xp[(size_t)gw*64 + lane];
  float a0 = fmaxf(fmaf(b2f_lo(v.x), sc[0], sh[0]), 0.f);
  float a1 = fmaxf(fmaf(b2f_hi(v.x), sc[1], sh[1]), 0.f);
  float a2 = fmaxf(fmaf(b2f_lo(v.y), sc[2], sh[2]), 0.f);
  float a3 = fmaxf(fmaf(b2f_hi(v.y), sc[3], sh[3]), 0.f);
  unsigned so0 = (unsigned)f2b(a0) | ((unsigned)f2b(a1) << 16);
  unsigned so1 = (unsigned)f2b(a2) | ((unsigned)f2b(a3) << 16);
  *(uint2*)(xc + (size_t)gw*KCAT + lane*4) = make_uint2(so0, so1);
  float c0 = 0.f, c1 = 0.f, c2 = 0.f, c3 = 0.f;
  int e = rp[gw], e1 = rp[gw+1];
  for (; e + 8 <= e1; e += 8){
    uint2 w[8];
    #pragma unroll
    for (int u = 0; u < 8; ++u) w[u] = xp[(size_t)es[e+u]*64 + lane];
    #pragma unroll
    for (int u = 0; u < 8; u += 2){
      a0 += fmaxf(fmaf(b2f_lo(w[u].x),   sc[0], sh[0]), 0.f);
      a1 += fmaxf(fmaf(b2f_hi(w[u].x),   sc[1], sh[1]), 0.f);
      a2 += fmaxf(fmaf(b2f_lo(w[u].y),   sc[2], sh[2]), 0.f);
      a3 += fmaxf(fmaf(b2f_hi(w[u].y),   sc[3], sh[3]), 0.f);
      c0 += fmaxf(fmaf(b2f_lo(w[u+1].x), sc[0], sh[0]), 0.f);
      c1 += fmaxf(fmaf(b2f_hi(w[u+1].x), sc[1], sh[1]), 0.f);
      c2 += fmaxf(fmaf(b2f_lo(w[u+1].y), sc[2], sh[2]), 0.f);
      c3 += fmaxf(fmaf(b2f_hi(w[u+1].y), sc[3], sh[3]), 0.f);
    }
  }
  for (; e < e1; ++e){
    uint2 w0 = xp[(size_t)es[e]*64 + lane];
    a0 += fmaxf(fmaf(b2f_lo(w0.x), sc[0], sh[0]), 0.f);
    a1 += fmaxf(fmaf(b2f_hi(w0.x), sc[1], sh[1]), 0.f);
    a2 += fmaxf(fmaf(b2f_lo(w0.y), sc[2], sh[2]), 0.f);
    a3 += fmaxf(fmaf(b2f_hi(w0.y), sc[3], sh[3]), 0.f);
  }
  a0 += c0; a1 += c1; a2 += c2; a3 += c3;
  unsigned o0 = (unsigned)f2b(a0) | ((unsigned)f2b(a1) << 16);
  unsigned o1 = (unsigned)f2b(a2) | ((unsigned)f2b(a3) << 16);
  *(uint2*)(agg + (size_t)gw*256 + lane*4) = make_uint2(o0, o1);
}

// ---------------- BN+ReLU (bf16 in, bf16 out, inline stats, strided output) ----------------
__global__ void k_bnrelu(const ushort_t* __restrict__ t, const float* __restrict__ sums,
                         const float* __restrict__ g, const float* __restrict__ b,
                         ushort_t* __restrict__ o, int ostride, int M, float invM){
  int idx = blockIdx.x*blockDim.x + threadIdx.x;
  if (idx >= M*(HID/8)) return;
  int row = idx >> 5, cg = (idx & 31) * 8;
  uint4 v = *(const uint4*)(t + (size_t)row*HID + cg);
  unsigned wv[4] = {v.x, v.y, v.z, v.w};
  unsigned ov[4];
  #pragma unroll
  for (int p = 0; p < 4; ++p){
    int c0 = cg + 2*p, c1 = c0 + 1;
    float m0 = sums[c0]*invM, m1 = sums[c1]*invM;
    float r0 = rsqrtf(sums[HID+c0]*invM - m0*m0 + 1e-5f);
    float r1 = rsqrtf(sums[HID+c1]*invM - m1*m1 + 1e-5f);
    float y0 = (b2f_lo(wv[p]) - m0)*r0*g[c0] + b[c0];
    float y1 = (b2f_hi(wv[p]) - m1)*r1*g[c1] + b[c1];
    y0 = y0 > 0.f ? y0 : 0.f; y1 = y1 > 0.f ? y1 : 0.f;
    ov[p] = (unsigned)f2b(y0) | ((unsigned)f2b(y1) << 16);
  }
  *(uint4*)(o + (size_t)row*ostride + cg) = make_uint4(ov[0], ov[1], ov[2], ov[3]);
}

// ---------------- h fp32 -> bf16 into xcat col 0..127 ----------------
__global__ void k_f2b(const float* __restrict__ in, ushort_t* __restrict__ xcat, int n8){
  int idx = blockIdx.x*blockDim.x + threadIdx.x;
  if (idx >= n8) return;
  int row = idx >> 4, cg = (idx & 15) * 8;
  float4 a = *(const float4*)(in + (size_t)row*IN_DIM + cg);
  float4 c = *(const float4*)(in + (size_t)row*IN_DIM + cg + 4);
  unsigned o0 = (unsigned)f2b(a.x) | ((unsigned)f2b(a.y) << 16);
  unsigned o1 = (unsigned)f2b(a.z) | ((unsigned)f2b(a.w) << 16);
  unsigned o2 = (unsigned)f2b(c.x) | ((unsigned)f2b(c.y) << 16);
  unsigned o3 = (unsigned)f2b(c.z) | ((unsigned)f2b(c.w) << 16);
  *(uint4*)(xcat + (size_t)row*KCAT + cg) = make_uint4(o0, o1, o2, o3);
}

// ---------------- weight transpose + convert (+ fused bias fold) ----------------
__global__ void k_wprep(const float* __restrict__ c0W1, const float* __restrict__ cW1,
                        const float* __restrict__ cW2, const float* __restrict__ p0W,
                        const float* __restrict__ pW,
                        const float* __restrict__ p0b, const float* __restrict__ pb,
                        ushort_t* __restrict__ wb, ushort_t* __restrict__ whead,
                        float* __restrict__ ball){
  int m = blockIdx.y;
  if (m == 13){
    if (blockIdx.x == 0 && threadIdx.x < OUT_DIM){
      int c = threadIdx.x;
      float v = p0b[c];
      #pragma unroll
      for (int i = 0; i < N_CONV; ++i) v += pb[i*OUT_DIM + c];
      ball[c] = v;
    }
    return;
  }
  const float* src; int R, C; ushort_t* dst; int dstride, dcol;
  if (m == 0){       src = c0W1;              R = 128; C = 256; dst = wb;                       dstride = 128;  dcol = 0; }
  else if (m <= 3){  src = cW1 + (m-1)*65536; R = 256; C = 256; dst = wb + 32768 + (m-1)*65536; dstride = 256;  dcol = 0; }
  else if (m <= 7){  src = cW2 + (m-4)*65536; R = 256; C = 256; dst = wb + 229376 + (m-4)*65536;dstride = 256;  dcol = 0; }
  else if (m == 8){  src = p0W;               R = 128; C = 64;  dst = whead;                    dstride = KCAT; dcol = 0; }
  else {             src = pW + (m-9)*16384;  R = 256; C = 64;  dst = whead;                    dstride = KCAT; dcol = 128 + (m-9)*256; }
  int tx = R/64, tiles = tx * (C/64);
  int t = blockIdx.x;
  if (t >= tiles) return;
  int sr0 = (t % tx)*64, sc0 = (t / tx)*64;
  __shared__ float ld[64][65];
  int c = threadIdx.x & 63, rq = threadIdx.x >> 6;
  #pragma unroll
  for (int i = 0; i < 16; ++i){
    int rr = i*4 + rq;
    ld[rr][c] = src[(size_t)(sr0+rr)*C + sc0 + c];
  }
  __syncthreads();
  #pragma unroll
  for (int i = 0; i < 16; ++i){
    int rr = i*4 + rq;
    dst[(size_t)(sc0+rr)*dstride + dcol + sr0 + c] = f2b(ld[c][rr]);
  }
}

// ---------------- MFMA GEMM: C[M,N] = A[M,K](bf16) @ BT[N,K](bf16)^T ----------------
// Double-buffered LDS (A and B via global_load_lds), one barrier per K-tile.
// MODE 0: round acc->bf16, fused column stats from rounded values, bf16 C (all rows incl pad)
// MODE 1: fp32 C + bias[col], masked row<M
// MODE 2: like MODE 0, but A reg-staged with fused BN(asums)+ReLU affine and pad-row zeroing
template<int BM, int BN, int MODE>
__global__ __launch_bounds__((BM/64)*(BN/64)*64)
void k_mgemm(const bf16* __restrict__ A, const bf16* __restrict__ BT,
             void* __restrict__ Cv, const float* __restrict__ bias,
             float* __restrict__ sums, const float* __restrict__ asums,
             const float* __restrict__ ag, const float* __restrict__ ab,
             int M, int N, int K, float invM)
{
  constexpr int NW  = (BM/64)*(BN/64);
  constexpr int WNT = BN/64;
  constexpr int ACH = BM/16, BCH = BN/16;
  __shared__ __align__(16) bf16 As[2*BM*32];
  __shared__ __align__(16) bf16 Bs[2*BN*32];
  __shared__ float sAf[MODE==2?256:1];
  __shared__ float tAf[MODE==2?256:1];
  const int tid = threadIdx.x;
  const int wid = tid >> 6, l = tid & 63;
  const int wm = wid / WNT, wn = wid % WNT;
  const int m0 = blockIdx.y * BM, n0 = blockIdx.x * BN;
  const int r = l & 15, q = l >> 4;
  const int fragByte = ((q ^ ((r >> 1) & 3)) << 4);
  const int wrow = l >> 2;
  const int wk = (((l & 3) ^ ((l >> 3) & 3)) << 3);

  if constexpr (MODE == 2){
    if (tid < 256){
      float m = asums[tid] * invM;
      float var = asums[256 + tid] * invM - m*m;
      float s = rsqrtf(var + 1e-5f) * ag[tid];
      sAf[tid] = s;
      tAf[tid] = ab[tid] - m*s;
    }
    __syncthreads();
  }

  auto STAGE = [&](int buf, int k0){
    #pragma unroll
    for (int c = 0; c < ACH/NW; ++c){
      int ch = wid + c*NW;
      if constexpr (MODE == 2){
        int grow = m0 + ch*16 + wrow;
        uint4 raw = *(const uint4*)(A + (size_t)grow*K + (k0 + wk));
        int kc = k0 + wk;
        unsigned rv[4] = {raw.x, raw.y, raw.z, raw.w};
        unsigned ov[4];
        #pragma unroll
        for (int p = 0; p < 4; ++p){
          int c0 = kc + 2*p, c1 = c0 + 1;
          float y0 = fmaf(b2f_lo(rv[p]), sAf[c0], tAf[c0]);
          float y1 = fmaf(b2f_hi(rv[p]), sAf[c1], tAf[c1]);
          y0 = y0 > 0.f ? y0 : 0.f; y1 = y1 > 0.f ? y1 : 0.f;
          ov[p] = (unsigned)f2b(y0) | ((unsigned)f2b(y1) << 16);
        }
        if (grow >= M){ ov[0]=0; ov[1]=0; ov[2]=0; ov[3]=0; }
        *(uint4*)((char*)As + buf*(BM*64) + ch*1024 + l*16) = make_uint4(ov[0],ov[1],ov[2],ov[3]);
      } else {
        const bf16* g = A + (size_t)(m0 + ch*16 + wrow)*K + (k0 + wk);
        stage16(g, (char*)As + buf*(BM*64) + ch*1024);
      }
    }
    #pragma unroll
    for (int c = 0; c < BCH/NW; ++c){
      int ch = wid + c*NW;
      const bf16* g = BT + (size_t)(n0 + ch*16 + wrow)*K + (k0 + wk);
      stage16(g, (char*)Bs + buf*(BN*64) + ch*1024);
    }
  };

  f32x4 acc[4][4] = {};
  const int nt = K >> 5;
  STAGE(0, 0);
  for (int t = 0; t < nt; ++t){
    int cur = t & 1;
    __syncthreads();
    if (t + 1 < nt) STAGE(cur ^ 1, (t + 1) << 5);
    bf16x8 af[4], bfr[4];
    #pragma unroll
    for (int mf = 0; mf < 4; ++mf)
      af[mf] = *(const bf16x8*)((const char*)As + cur*(BM*64) + (wm*64 + mf*16 + r)*64 + fragByte);
    #pragma unroll
    for (int nf = 0; nf < 4; ++nf)
      bfr[nf] = *(const bf16x8*)((const char*)Bs + cur*(BN*64) + (wn*64 + nf*16 + r)*64 + fragByte);
    #pragma unroll
    for (int mf = 0; mf < 4; ++mf)
      #pragma unroll
      for (int nf = 0; nf < 4; ++nf)
        acc[mf][nf] = __builtin_amdgcn_mfma_f32_16x16x32_bf16(af[mf], bfr[nf], acc[mf][nf], 0, 0, 0);
  }

  if (MODE == 0 || MODE == 2){
    ushort_t* Cb = (ushort_t*)Cv;
    float s1[4] = {0.f,0.f,0.f,0.f}, s2[4] = {0.f,0.f,0.f,0.f};
    #pragma unroll
    for (int mf = 0; mf < 4; ++mf){
      #pragma unroll
      for (int j = 0; j < 4; ++j){
        int row = m0 + wm*64 + mf*16 + q*4 + j;
        #pragma unroll
        for (int nf = 0; nf < 4; ++nf){
          unsigned short us = f2b(acc[mf][nf][j]);
          float vr = __uint_as_float((unsigned)us << 16);
          s1[nf] += vr; s2[nf] = fmaf(vr, vr, s2[nf]);
          Cb[(size_t)row*N + n0 + wn*64 + nf*16 + r] = us;
        }
      }
    }
    #pragma unroll
    for (int nf = 0; nf < 4; ++nf){
      float a = s1[nf], c = s2[nf];
      a += __shfl_xor(a, 16, 64); a += __shfl_xor(a, 32, 64);
      c += __shfl_xor(c, 16, 64); c += __shfl_xor(c, 32, 64);
      if (q == 0){
        int col = n0 + wn*64 + nf*16 + r;
        atomicAdd(&sums[col], a);
        atomicAdd(&sums[256 + col], c);
      }
    }
  } else {
    float* C = (float*)Cv;
    #pragma unroll
    for (int mf = 0; mf < 4; ++mf){
      #pragma unroll
      for (int j = 0; j < 4; ++j){
        int row = m0 + wm*64 + mf*16 + q*4 + j;
        if (row >= M) continue;
        #pragma unroll
        for (int nf = 0; nf < 4; ++nf){
          int col = n0 + wn*64 + nf*16 + r;
          C[(size_t)row*N + col] = acc[mf][nf][j] + bias[col];
        }
      }
    }
  }
}

extern "C" void kernel_launch(void* const* d_in, const int* in_sizes, int n_in,
                              void* d_out, int out_size, void* d_ws, size_t ws_size,
                              hipStream_t stream){
  const float* h    = (const float*)d_in[0];
  const float* c0W1 = (const float*)d_in[1];
  const float* cW1  = (const float*)d_in[2];
  const float* cW2  = (const float*)d_in[3];
  const float* bn1g = (const float*)d_in[4];
  const float* bn1b = (const float*)d_in[5];
  const float* bn2g = (const float*)d_in[6];
  const float* bn2b = (const float*)d_in[7];
  const float* p0W  = (const float*)d_in[8];
  const float* p0b  = (const float*)d_in[9];
  const float* pW   = (const float*)d_in[10];
  const float* pb   = (const float*)d_in[11];
  const int* src    = (const int*)d_in[12];
  const int* dst    = (const int*)d_in[13];
  float* out = (float*)d_out;

  char* w = (char*)d_ws;
  auto alloc = [&](size_t bytes)->char*{ char* p = w; w += (bytes + 255) & ~(size_t)255; return p; };
  ushort_t* xcat = (ushort_t*)alloc((size_t)MPAD*KCAT*2);
  ushort_t* aggb = (ushort_t*)alloc((size_t)MPAD*HID*2);
  ushort_t* tt   = (ushort_t*)alloc((size_t)MPAD*HID*2);
  ushort_t* wb   = (ushort_t*)alloc((size_t)491520*2);
  ushort_t* whead= (ushort_t*)alloc((size_t)OUT_DIM*KCAT*2);
  int* row_ptr   = (int*)alloc((N_NODES+1)*4);
  int* cursor    = (int*)alloc(N_NODES*4);
  int* counts    = (int*)alloc(N_NODES*4);
  int* esrc      = (int*)alloc(N_EDGES*4);
  int* scanned   = (int*)alloc(N_NODES*4);
  int* bsum      = (int*)alloc(256*4);
  float* sums8   = (float*)alloc(8*512*4);
  float* ball    = (float*)alloc(OUT_DIM*4);

  // pad-row zeroing (aggb 128-wide + 256-wide views) + sums + counts, one dispatch
  {
    const int PADR = MPAD - N_NODES;
    int n0 = PADR*IN_DIM*2, n1 = PADR*HID*2, n2 = 8*512*4, n3 = N_NODES*4;
    int chunks = (n0 + n1 + n2 + n3) / 16;
    k_zero<<<(chunks + 255)/256, 256, 0, stream>>>(
        (char*)(aggb + (size_t)N_NODES*IN_DIM), n0,
        (char*)(aggb + (size_t)N_NODES*HID), n1,
        (char*)sums8, n2, (char*)counts, n3);
  }

  // ---- CSR build (by dst) ----
  const int NB = (N_NODES + 255) / 256;
  k_count<<<(N_EDGES+255)/256, 256, 0, stream>>>(dst, counts, N_EDGES);
  k_scan1<<<NB, 256, 0, stream>>>(counts, scanned, bsum, N_NODES);
  k_scan2<<<1, 256, 0, stream>>>(bsum, NB);
  k_scan3<<<NB, 256, 0, stream>>>(scanned, bsum, counts, row_ptr, cursor, N_NODES);
  k_fill<<<(N_EDGES+255)/256, 256, 0, stream>>>(src, dst, cursor, esrc, N_EDGES);

  // ---- weight prep (+bias fold) + h->xcat ----
  k_wprep<<<dim3(16, 14), 256, 0, stream>>>(c0W1, cW1, cW2, p0W, pW, p0b, pb, wb, whead, ball);
  k_f2b<<<(N_NODES*16 + 255)/256, 256, 0, stream>>>(h, xcat, N_NODES*16);

  const float invM = 1.0f / (float)N_NODES;
  // Buffer ping-pong per layer: agg-out = P, GEMM1: P->Q, GEMM2: Q->P (raw out).
  ushort_t* raw = nullptr;   // raw GEMM2 output of previous layer
  for (int i = 0; i < N_CONV; ++i){
    int K1 = (i == 0) ? IN_DIM : HID;
    ushort_t* aout = (i == 0) ? aggb : ((i & 1) ? tt : aggb);   // agg output buffer
    ushort_t* g1o  = (i & 1) ? aggb : tt;                       // GEMM1 output
    float* sums1 = sums8 + (size_t)(2*i)*512;
    float* sums2 = sums8 + (size_t)(2*i+1)*512;

    if (i == 0)
      k_agg0<<<(N_NODES*64+255)/256, 256, 0, stream>>>(xcat, row_ptr, esrc, aggb, N_NODES);
    else
      k_aggbn<<<(N_NODES*64+255)/256, 256, 0, stream>>>(
          raw, row_ptr, esrc, aout, xcat + 128 + (size_t)(i-1)*HID,
          sums8 + (size_t)(2*(i-1)+1)*512, bn2g + (i-1)*HID, bn2b + (i-1)*HID,
          invM, N_NODES);

    // GEMM1: g1o = aout @ W1  (+ fused stats of rounded output)
    const ushort_t* W1T = (i == 0) ? wb : (wb + 32768 + (size_t)(i-1)*65536);
    k_mgemm<64, 256, 0><<<dim3(1, MPAD/64), 256, 0, stream>>>(
        (const bf16*)aout, (const bf16*)W1T, g1o, nullptr, sums1,
        nullptr, nullptr, nullptr, N_NODES, HID, K1, invM);

    // GEMM2: aout = relu(bn1(g1o)) @ W2  (BN1+ReLU fused into A-staging; fused stats)
    const ushort_t* W2T = wb + 229376 + (size_t)i*65536;
    k_mgemm<64, 256, 2><<<dim3(1, MPAD/64), 256, 0, stream>>>(
        (const bf16*)g1o, (const bf16*)W2T, aout, nullptr, sums2,
        sums1, bn1g + i*HID, bn1b + i*HID, N_NODES, HID, HID, invM);
    raw = aout;
  }

  // final BN2+ReLU for layer 3 -> xcat slice 3
  k_bnrelu<<<(N_NODES*32 + 255)/256, 256, 0, stream>>>(
      raw, sums8 + 7*512, bn2g + 3*HID, bn2b + 3*HID,
      xcat + 128 + (size_t)3*HID, KCAT, N_NODES, invM);

  // ---- consolidated jumping-knowledge head GEMM: out = xcat @ whead^T + ball ----
  k_mgemm<128, 64, 1><<<dim3(1, MPAD/128), 128, 0, stream>>>(
      (const bf16*)xcat, (const bf16*)whead, out, ball, nullptr,
      nullptr, nullptr, nullptr, N_NODES, OUT_DIM, KCAT, invM);
}

// Round 9
// 676.968 us; speedup vs baseline: 1.0488x; 1.0137x over previous
//
#include <hip/hip_runtime.h>

#define N_NODES 50000
#define MPAD    50176
#define N_EDGES 800000
#define IN_DIM 128
#define HID 256
#define OUT_DIM 64
#define N_CONV 4
#define KCAT 1152   // 128 + 4*256

typedef __bf16 bf16;
typedef __attribute__((ext_vector_type(8))) __bf16 bf16x8;
typedef __attribute__((ext_vector_type(4))) float f32x4;
typedef unsigned short ushort_t;

__device__ __forceinline__ unsigned short f2b(float f){
  unsigned u = __float_as_uint(f);
  u += 0x7fffu + ((u >> 16) & 1u);
  return (unsigned short)(u >> 16);
}
__device__ __forceinline__ float b2f_lo(unsigned v){ return __uint_as_float(v << 16); }
__device__ __forceinline__ float b2f_hi(unsigned v){ return __uint_as_float(v & 0xffff0000u); }

__device__ __forceinline__ void stage16(const void* g, void* l){
  __builtin_amdgcn_global_load_lds((const __attribute__((address_space(1))) unsigned int*)g,
                                   (__attribute__((address_space(3))) unsigned int*)l, 16, 0, 0);
}

// ---------------- CSR build ----------------
__global__ void k_count(const int* __restrict__ dst, int* __restrict__ cnt, int ne){
  int e = blockIdx.x*blockDim.x + threadIdx.x;
  if (e < ne) atomicAdd(&cnt[dst[e]], 1);
}

__global__ void k_scan1(const int* __restrict__ cnt, int* __restrict__ scanned,
                        int* __restrict__ bsum, int n){
  int i = blockIdx.x*256 + threadIdx.x;
  int v = (i < n) ? cnt[i] : 0;
  int lane = threadIdx.x & 63;
  #pragma unroll
  for (int off = 1; off < 64; off <<= 1){
    int t = __shfl_up(v, off, 64);
    if (lane >= off) v += t;
  }
  __shared__ int wsum[4];
  int wv = threadIdx.x >> 6;
  if (lane == 63) wsum[wv] = v;
  __syncthreads();
  if (threadIdx.x == 0){
    int s = 0;
    #pragma unroll
    for (int k = 0; k < 4; ++k){ int t = wsum[k]; wsum[k] = s; s += t; }
    bsum[blockIdx.x] = s;
  }
  __syncthreads();
  v += wsum[wv];
  if (i < n) scanned[i] = v;
}

__global__ void k_scan2(int* __restrict__ bsum, int nb){
  __shared__ int sd[256];
  int i = threadIdx.x;
  sd[i] = (i < nb) ? bsum[i] : 0;
  __syncthreads();
  #pragma unroll
  for (int off = 1; off < 256; off <<= 1){
    int t = (i >= off) ? sd[i-off] : 0;
    __syncthreads();
    sd[i] += t;
    __syncthreads();
  }
  if (i < nb) bsum[i] = sd[i];
}

__global__ void k_scan3(const int* __restrict__ scanned, const int* __restrict__ bsum,
                        const int* __restrict__ cnt, int* __restrict__ row_ptr,
                        int* __restrict__ cursor, int n){
  int i = blockIdx.x*256 + threadIdx.x;
  if (i < n){
    int off = (blockIdx.x > 0) ? bsum[blockIdx.x-1] : 0;
    int inc = scanned[i] + off;
    row_ptr[i+1] = inc;
    cursor[i] = inc - cnt[i];
  }
  if (i == 0) row_ptr[0] = 0;
}

__global__ void k_fill(const int* __restrict__ src, const int* __restrict__ dst,
                       int* __restrict__ cursor, int* __restrict__ esrc, int ne){
  int e = blockIdx.x*blockDim.x + threadIdx.x;
  if (e < ne){
    int p = atomicAdd(&cursor[dst[e]], 1);
    esrc[p] = src[e];
  }
}

// ---------------- zero helper: 4 byte-ranges in one dispatch ----------------
__global__ void k_zero(char* p0, int n0, char* p1, int n1, char* p2, int n2, char* p3, int n3){
  int i = (blockIdx.x*blockDim.x + threadIdx.x) * 16;
  if (i < n0) *(uint4*)(p0 + i) = make_uint4(0,0,0,0);
  i -= n0;
  if (i >= 0 && i < n1) *(uint4*)(p1 + i) = make_uint4(0,0,0,0);
  i -= n1;
  if (i >= 0 && i < n2) *(uint4*)(p2 + i) = make_uint4(0,0,0,0);
  i -= n2;
  if (i >= 0 && i < n3) *(uint4*)(p3 + i) = make_uint4(0,0,0,0);
}

// ---------------- aggregation from xcat slice (bf16, fp32 accum, 8x MLP) ----------------
template<int D>
__global__ void k_agg(const ushort_t* __restrict__ x, const int* __restrict__ rp,
                      const int* __restrict__ es, ushort_t* __restrict__ agg, int n){
  int gw = (int)((blockIdx.x*(size_t)blockDim.x + threadIdx.x) >> 6);
  int lane = threadIdx.x & 63;
  if (gw >= n) return;
  if (D == 256){
    const uint2* xp = (const uint2*)x; const int S = KCAT/4;
    uint2 v = xp[(size_t)gw*S + lane];
    float a0=b2f_lo(v.x), a1=b2f_hi(v.x), a2=b2f_lo(v.y), a3=b2f_hi(v.y);
    float c0=0.f, c1=0.f, c2=0.f, c3=0.f;
    int e = rp[gw], e1 = rp[gw+1];
    for (; e + 8 <= e1; e += 8){
      uint2 w[8];
      #pragma unroll
      for (int u = 0; u < 8; ++u) w[u] = xp[(size_t)es[e+u]*S + lane];
      #pragma unroll
      for (int u = 0; u < 8; u += 2){
        a0 += b2f_lo(w[u].x);   a1 += b2f_hi(w[u].x);   a2 += b2f_lo(w[u].y);   a3 += b2f_hi(w[u].y);
        c0 += b2f_lo(w[u+1].x); c1 += b2f_hi(w[u+1].x); c2 += b2f_lo(w[u+1].y); c3 += b2f_hi(w[u+1].y);
      }
    }
    for (; e + 2 <= e1; e += 2){
      uint2 w0 = xp[(size_t)es[e]*S + lane];
      uint2 w1 = xp[(size_t)es[e+1]*S + lane];
      a0 += b2f_lo(w0.x); a1 += b2f_hi(w0.x); a2 += b2f_lo(w0.y); a3 += b2f_hi(w0.y);
      c0 += b2f_lo(w1.x); c1 += b2f_hi(w1.x); c2 += b2f_lo(w1.y); c3 += b2f_hi(w1.y);
    }
    if (e < e1){
      uint2 w0 = xp[(size_t)es[e]*S + lane];
      a0 += b2f_lo(w0.x); a1 += b2f_hi(w0.x); a2 += b2f_lo(w0.y); a3 += b2f_hi(w0.y);
    }
    a0 += c0; a1 += c1; a2 += c2; a3 += c3;
    unsigned o0 = (unsigned)f2b(a0) | ((unsigned)f2b(a1) << 16);
    unsigned o1 = (unsigned)f2b(a2) | ((unsigned)f2b(a3) << 16);
    *(uint2*)(agg + (size_t)gw*256 + lane*4) = make_uint2(o0, o1);
  } else {
    const unsigned* xp = (const unsigned*)x; const int S = KCAT/2;
    unsigned v = xp[(size_t)gw*S + lane];
    float a0 = b2f_lo(v), a1 = b2f_hi(v);
    float c0 = 0.f, c1 = 0.f;
    int e = rp[gw], e1 = rp[gw+1];
    for (; e + 8 <= e1; e += 8){
      unsigned w[8];
      #pragma unroll
      for (int u = 0; u < 8; ++u) w[u] = xp[(size_t)es[e+u]*S + lane];
      #pragma unroll
      for (int u = 0; u < 8; u += 2){
        a0 += b2f_lo(w[u]);   a1 += b2f_hi(w[u]);
        c0 += b2f_lo(w[u+1]); c1 += b2f_hi(w[u+1]);
      }
    }
    for (; e + 2 <= e1; e += 2){
      unsigned w0 = xp[(size_t)es[e]*S + lane];
      unsigned w1 = xp[(size_t)es[e+1]*S + lane];
      a0 += b2f_lo(w0); a1 += b2f_hi(w0);
      c0 += b2f_lo(w1); c1 += b2f_hi(w1);
    }
    if (e < e1){
      unsigned w0 = xp[(size_t)es[e]*S + lane];
      a0 += b2f_lo(w0); a1 += b2f_hi(w0);
    }
    a0 += c0; a1 += c1;
    unsigned o = (unsigned)f2b(a0) | ((unsigned)f2b(a1) << 16);
    *(unsigned*)(agg + (size_t)gw*128 + lane*2) = o;
  }
}

// ---------------- BN+ReLU (bf16 in, bf16 out, inline stats, strided output) ----------------
__global__ void k_bnrelu(const ushort_t* __restrict__ t, const float* __restrict__ sums,
                         const float* __restrict__ g, const float* __restrict__ b,
                         ushort_t* __restrict__ o, int ostride, int M, float invM){
  int idx = blockIdx.x*blockDim.x + threadIdx.x;
  if (idx >= M*(HID/8)) return;
  int row = idx >> 5, cg = (idx & 31) * 8;
  uint4 v = *(const uint4*)(t + (size_t)row*HID + cg);
  unsigned wv[4] = {v.x, v.y, v.z, v.w};
  unsigned ov[4];
  #pragma unroll
  for (int p = 0; p < 4; ++p){
    int c0 = cg + 2*p, c1 = c0 + 1;
    float m0 = sums[c0]*invM, m1 = sums[c1]*invM;
    float r0 = rsqrtf(sums[HID+c0]*invM - m0*m0 + 1e-5f);
    float r1 = rsqrtf(sums[HID+c1]*invM - m1*m1 + 1e-5f);
    float y0 = (b2f_lo(wv[p]) - m0)*r0*g[c0] + b[c0];
    float y1 = (b2f_hi(wv[p]) - m1)*r1*g[c1] + b[c1];
    y0 = y0 > 0.f ? y0 : 0.f; y1 = y1 > 0.f ? y1 : 0.f;
    ov[p] = (unsigned)f2b(y0) | ((unsigned)f2b(y1) << 16);
  }
  *(uint4*)(o + (size_t)row*ostride + cg) = make_uint4(ov[0], ov[1], ov[2], ov[3]);
}

// ---------------- h fp32 -> bf16 into xcat col 0..127 ----------------
__global__ void k_f2b(const float* __restrict__ in, ushort_t* __restrict__ xcat, int n8){
  int idx = blockIdx.x*blockDim.x + threadIdx.x;
  if (idx >= n8) return;
  int row = idx >> 4, cg = (idx & 15) * 8;
  float4 a = *(const float4*)(in + (size_t)row*IN_DIM + cg);
  float4 c = *(const float4*)(in + (size_t)row*IN_DIM + cg + 4);
  unsigned o0 = (unsigned)f2b(a.x) | ((unsigned)f2b(a.y) << 16);
  unsigned o1 = (unsigned)f2b(a.z) | ((unsigned)f2b(a.w) << 16);
  unsigned o2 = (unsigned)f2b(c.x) | ((unsigned)f2b(c.y) << 16);
  unsigned o3 = (unsigned)f2b(c.z) | ((unsigned)f2b(c.w) << 16);
  *(uint4*)(xcat + (size_t)row*KCAT + cg) = make_uint4(o0, o1, o2, o3);
}

// ---------------- weight transpose + convert (+ fused bias fold) ----------------
__global__ void k_wprep(const float* __restrict__ c0W1, const float* __restrict__ cW1,
                        const float* __restrict__ cW2, const float* __restrict__ p0W,
                        const float* __restrict__ pW,
                        const float* __restrict__ p0b, const float* __restrict__ pb,
                        ushort_t* __restrict__ wb, ushort_t* __restrict__ whead,
                        float* __restrict__ ball){
  int m = blockIdx.y;
  if (m == 13){
    if (blockIdx.x == 0 && threadIdx.x < OUT_DIM){
      int c = threadIdx.x;
      float v = p0b[c];
      #pragma unroll
      for (int i = 0; i < N_CONV; ++i) v += pb[i*OUT_DIM + c];
      ball[c] = v;
    }
    return;
  }
  const float* src; int R, C; ushort_t* dst; int dstride, dcol;
  if (m == 0){       src = c0W1;              R = 128; C = 256; dst = wb;                       dstride = 128;  dcol = 0; }
  else if (m <= 3){  src = cW1 + (m-1)*65536; R = 256; C = 256; dst = wb + 32768 + (m-1)*65536; dstride = 256;  dcol = 0; }
  else if (m <= 7){  src = cW2 + (m-4)*65536; R = 256; C = 256; dst = wb + 229376 + (m-4)*65536;dstride = 256;  dcol = 0; }
  else if (m == 8){  src = p0W;               R = 128; C = 64;  dst = whead;                    dstride = KCAT; dcol = 0; }
  else {             src = pW + (m-9)*16384;  R = 256; C = 64;  dst = whead;                    dstride = KCAT; dcol = 128 + (m-9)*256; }
  int tx = R/64, tiles = tx * (C/64);
  int t = blockIdx.x;
  if (t >= tiles) return;
  int sr0 = (t % tx)*64, sc0 = (t / tx)*64;
  __shared__ float ld[64][65];
  int c = threadIdx.x & 63, rq = threadIdx.x >> 6;
  #pragma unroll
  for (int i = 0; i < 16; ++i){
    int rr = i*4 + rq;
    ld[rr][c] = src[(size_t)(sr0+rr)*C + sc0 + c];
  }
  __syncthreads();
  #pragma unroll
  for (int i = 0; i < 16; ++i){
    int rr = i*4 + rq;
    dst[(size_t)(sc0+rr)*dstride + dcol + sr0 + c] = f2b(ld[c][rr]);
  }
}

// ---------------- MFMA GEMM: C[M,N] = A[M,K](bf16) @ BT[N,K](bf16)^T ----------------
// Double-buffered LDS (A and B via global_load_lds), one barrier per K-tile.
// MODE 0: round acc->bf16, fused column stats from rounded values, bf16 C (all rows incl pad)
// MODE 1: fp32 C + bias[col], masked row<M
// MODE 2: like MODE 0, but A reg-staged with fused BN(asums)+ReLU affine and pad-row zeroing
// MODE 3: like MODE 1, but A is hybrid: k<896 stage16 from A (xcat); k>=896 reg-staged from
//         A2 (raw layer-3 GEMM2 out, stride HID) with fused BN(asums)+ReLU affine
template<int BM, int BN, int MODE>
__global__ __launch_bounds__((BM/64)*(BN/64)*64)
void k_mgemm(const bf16* __restrict__ A, const bf16* __restrict__ BT,
             void* __restrict__ Cv, const float* __restrict__ bias,
             float* __restrict__ sums, const float* __restrict__ asums,
             const float* __restrict__ ag, const float* __restrict__ ab,
             const bf16* __restrict__ A2,
             int M, int N, int K, float invM)
{
  constexpr int NW  = (BM/64)*(BN/64);
  constexpr int WNT = BN/64;
  constexpr int ACH = BM/16, BCH = BN/16;
  __shared__ __align__(16) bf16 As[2*BM*32];
  __shared__ __align__(16) bf16 Bs[2*BN*32];
  __shared__ float sAf[(MODE>=2)?256:1];
  __shared__ float tAf[(MODE>=2)?256:1];
  const int tid = threadIdx.x;
  const int wid = tid >> 6, l = tid & 63;
  const int wm = wid / WNT, wn = wid % WNT;
  const int m0 = blockIdx.y * BM, n0 = blockIdx.x * BN;
  const int r = l & 15, q = l >> 4;
  const int fragByte = ((q ^ ((r >> 1) & 3)) << 4);
  const int wrow = l >> 2;
  const int wk = (((l & 3) ^ ((l >> 3) & 3)) << 3);

  if constexpr (MODE >= 2){
    for (int c = tid; c < 256; c += NW*64){
      float m = asums[c] * invM;
      float var = asums[256 + c] * invM - m*m;
      float s = rsqrtf(var + 1e-5f) * ag[c];
      sAf[c] = s;
      tAf[c] = ab[c] - m*s;
    }
    __syncthreads();
  }

  auto REGSTAGE_A = [&](int buf, int ch, const bf16* srcRow, int kc){
    // srcRow points at element kc-base of the row; kc = affine column of first elem
    uint4 raw = *(const uint4*)(srcRow);
    unsigned rv[4] = {raw.x, raw.y, raw.z, raw.w};
    unsigned ov[4];
    #pragma unroll
    for (int p = 0; p < 4; ++p){
      int c0 = kc + 2*p, c1 = c0 + 1;
      float y0 = fmaf(b2f_lo(rv[p]), sAf[c0], tAf[c0]);
      float y1 = fmaf(b2f_hi(rv[p]), sAf[c1], tAf[c1]);
      y0 = y0 > 0.f ? y0 : 0.f; y1 = y1 > 0.f ? y1 : 0.f;
      ov[p] = (unsigned)f2b(y0) | ((unsigned)f2b(y1) << 16);
    }
    int grow = m0 + ch*16 + wrow;
    if (grow >= M){ ov[0]=0; ov[1]=0; ov[2]=0; ov[3]=0; }
    *(uint4*)((char*)As + buf*(BM*64) + ch*1024 + l*16) = make_uint4(ov[0],ov[1],ov[2],ov[3]);
  };

  auto STAGE = [&](int buf, int k0){
    #pragma unroll
    for (int c = 0; c < ACH/NW; ++c){
      int ch = wid + c*NW;
      int grow = m0 + ch*16 + wrow;
      if constexpr (MODE == 2){
        REGSTAGE_A(buf, ch, A + (size_t)grow*K + (k0 + wk), k0 + wk);
      } else if constexpr (MODE == 3){
        if (k0 < 896){
          const bf16* g = A + (size_t)grow*K + (k0 + wk);
          stage16(g, (char*)As + buf*(BM*64) + ch*1024);
        } else {
          int kc = k0 - 896 + wk;
          REGSTAGE_A(buf, ch, A2 + (size_t)grow*HID + kc, kc);
        }
      } else {
        const bf16* g = A + (size_t)grow*K + (k0 + wk);
        stage16(g, (char*)As + buf*(BM*64) + ch*1024);
      }
    }
    #pragma unroll
    for (int c = 0; c < BCH/NW; ++c){
      int ch = wid + c*NW;
      const bf16* g = BT + (size_t)(n0 + ch*16 + wrow)*K + (k0 + wk);
      stage16(g, (char*)Bs + buf*(BN*64) + ch*1024);
    }
  };

  f32x4 acc[4][4] = {};
  const int nt = K >> 5;
  STAGE(0, 0);
  for (int t = 0; t < nt; ++t){
    int cur = t & 1;
    __syncthreads();
    if (t + 1 < nt) STAGE(cur ^ 1, (t + 1) << 5);
    bf16x8 af[4], bfr[4];
    #pragma unroll
    for (int mf = 0; mf < 4; ++mf)
      af[mf] = *(const bf16x8*)((const char*)As + cur*(BM*64) + (wm*64 + mf*16 + r)*64 + fragByte);
    #pragma unroll
    for (int nf = 0; nf < 4; ++nf)
      bfr[nf] = *(const bf16x8*)((const char*)Bs + cur*(BN*64) + (wn*64 + nf*16 + r)*64 + fragByte);
    #pragma unroll
    for (int mf = 0; mf < 4; ++mf)
      #pragma unroll
      for (int nf = 0; nf < 4; ++nf)
        acc[mf][nf] = __builtin_amdgcn_mfma_f32_16x16x32_bf16(af[mf], bfr[nf], acc[mf][nf], 0, 0, 0);
  }

  if (MODE == 0 || MODE == 2){
    ushort_t* Cb = (ushort_t*)Cv;
    float s1[4] = {0.f,0.f,0.f,0.f}, s2[4] = {0.f,0.f,0.f,0.f};
    #pragma unroll
    for (int mf = 0; mf < 4; ++mf){
      #pragma unroll
      for (int j = 0; j < 4; ++j){
        int row = m0 + wm*64 + mf*16 + q*4 + j;
        #pragma unroll
        for (int nf = 0; nf < 4; ++nf){
          unsigned short us = f2b(acc[mf][nf][j]);
          float vr = __uint_as_float((unsigned)us << 16);
          s1[nf] += vr; s2[nf] = fmaf(vr, vr, s2[nf]);
          Cb[(size_t)row*N + n0 + wn*64 + nf*16 + r] = us;
        }
      }
    }
    #pragma unroll
    for (int nf = 0; nf < 4; ++nf){
      float a = s1[nf], c = s2[nf];
      a += __shfl_xor(a, 16, 64); a += __shfl_xor(a, 32, 64);
      c += __shfl_xor(c, 16, 64); c += __shfl_xor(c, 32, 64);
      if (q == 0){
        int col = n0 + wn*64 + nf*16 + r;
        atomicAdd(&sums[col], a);
        atomicAdd(&sums[256 + col], c);
      }
    }
  } else {
    float* C = (float*)Cv;
    #pragma unroll
    for (int mf = 0; mf < 4; ++mf){
      #pragma unroll
      for (int j = 0; j < 4; ++j){
        int row = m0 + wm*64 + mf*16 + q*4 + j;
        if (row >= M) continue;
        #pragma unroll
        for (int nf = 0; nf < 4; ++nf){
          int col = n0 + wn*64 + nf*16 + r;
          C[(size_t)row*N + col] = acc[mf][nf][j] + bias[col];
        }
      }
    }
  }
}

extern "C" void kernel_launch(void* const* d_in, const int* in_sizes, int n_in,
                              void* d_out, int out_size, void* d_ws, size_t ws_size,
                              hipStream_t stream){
  const float* h    = (const float*)d_in[0];
  const float* c0W1 = (const float*)d_in[1];
  const float* cW1  = (const float*)d_in[2];
  const float* cW2  = (const float*)d_in[3];
  const float* bn1g = (const float*)d_in[4];
  const float* bn1b = (const float*)d_in[5];
  const float* bn2g = (const float*)d_in[6];
  const float* bn2b = (const float*)d_in[7];
  const float* p0W  = (const float*)d_in[8];
  const float* p0b  = (const float*)d_in[9];
  const float* pW   = (const float*)d_in[10];
  const float* pb   = (const float*)d_in[11];
  const int* src    = (const int*)d_in[12];
  const int* dst    = (const int*)d_in[13];
  float* out = (float*)d_out;

  char* w = (char*)d_ws;
  auto alloc = [&](size_t bytes)->char*{ char* p = w; w += (bytes + 255) & ~(size_t)255; return p; };
  ushort_t* xcat = (ushort_t*)alloc((size_t)MPAD*KCAT*2);
  ushort_t* aggb = (ushort_t*)alloc((size_t)MPAD*HID*2);
  ushort_t* tt   = (ushort_t*)alloc((size_t)MPAD*HID*2);
  ushort_t* wb   = (ushort_t*)alloc((size_t)491520*2);
  ushort_t* whead= (ushort_t*)alloc((size_t)OUT_DIM*KCAT*2);
  int* row_ptr   = (int*)alloc((N_NODES+1)*4);
  int* cursor    = (int*)alloc(N_NODES*4);
  int* counts    = (int*)alloc(N_NODES*4);
  int* esrc      = (int*)alloc(N_EDGES*4);
  int* scanned   = (int*)alloc(N_NODES*4);
  int* bsum      = (int*)alloc(256*4);
  float* sums8   = (float*)alloc(8*512*4);
  float* ball    = (float*)alloc(OUT_DIM*4);

  // pad-row zeroing (aggb 128-wide + 256-wide views) + sums + counts, one dispatch
  {
    const int PADR = MPAD - N_NODES;
    int n0 = PADR*IN_DIM*2, n1 = PADR*HID*2, n2 = 8*512*4, n3 = N_NODES*4;
    int chunks = (n0 + n1 + n2 + n3) / 16;
    k_zero<<<(chunks + 255)/256, 256, 0, stream>>>(
        (char*)(aggb + (size_t)N_NODES*IN_DIM), n0,
        (char*)(aggb + (size_t)N_NODES*HID), n1,
        (char*)sums8, n2, (char*)counts, n3);
  }

  // ---- CSR build (by dst) ----
  const int NB = (N_NODES + 255) / 256;
  k_count<<<(N_EDGES+255)/256, 256, 0, stream>>>(dst, counts, N_EDGES);
  k_scan1<<<NB, 256, 0, stream>>>(counts, scanned, bsum, N_NODES);
  k_scan2<<<1, 256, 0, stream>>>(bsum, NB);
  k_scan3<<<NB, 256, 0, stream>>>(scanned, bsum, counts, row_ptr, cursor, N_NODES);
  k_fill<<<(N_EDGES+255)/256, 256, 0, stream>>>(src, dst, cursor, esrc, N_EDGES);

  // ---- weight prep (+bias fold) + h->xcat ----
  k_wprep<<<dim3(16, 14), 256, 0, stream>>>(c0W1, cW1, cW2, p0W, pW, p0b, pb, wb, whead, ball);
  k_f2b<<<(N_NODES*16 + 255)/256, 256, 0, stream>>>(h, xcat, N_NODES*16);

  const float invM = 1.0f / (float)N_NODES;
  for (int i = 0; i < N_CONV; ++i){
    int K1 = (i == 0) ? IN_DIM : HID;
    const ushort_t* xin = (i == 0) ? xcat : (xcat + 128 + (size_t)(i-1)*HID);
    if (i == 0)
      k_agg<IN_DIM><<<(N_NODES*64+255)/256, 256, 0, stream>>>(xin, row_ptr, esrc, aggb, N_NODES);
    else
      k_agg<HID><<<(N_NODES*64+255)/256, 256, 0, stream>>>(xin, row_ptr, esrc, aggb, N_NODES);

    float* sums1 = sums8 + (size_t)(2*i)*512;
    float* sums2 = sums8 + (size_t)(2*i+1)*512;

    // GEMM1: tt = aggb @ W1  (+ fused stats of rounded output)
    const ushort_t* W1T = (i == 0) ? wb : (wb + 32768 + (size_t)(i-1)*65536);
    k_mgemm<64, 256, 0><<<dim3(1, MPAD/64), 256, 0, stream>>>(
        (const bf16*)aggb, (const bf16*)W1T, tt, nullptr, sums1,
        nullptr, nullptr, nullptr, nullptr, N_NODES, HID, K1, invM);

    // GEMM2: aggb = relu(bn1(tt)) @ W2  (BN1+ReLU fused into A-staging; fused stats)
    const ushort_t* W2T = wb + 229376 + (size_t)i*65536;
    k_mgemm<64, 256, 2><<<dim3(1, MPAD/64), 256, 0, stream>>>(
        (const bf16*)tt, (const bf16*)W2T, aggb, nullptr, sums2,
        sums1, bn1g + i*HID, bn1b + i*HID, nullptr, N_NODES, HID, HID, invM);

    // BN2+ReLU -> xcat slice (layers 0..2; layer 3 fused into head GEMM)
    if (i < 3)
      k_bnrelu<<<(N_NODES*32 + 255)/256, 256, 0, stream>>>(
          aggb, sums2, bn2g + i*HID, bn2b + i*HID, xcat + 128 + (size_t)i*HID, KCAT, N_NODES, invM);
  }

  // ---- consolidated jumping-knowledge head GEMM: out = xcat @ whead^T + ball ----
  // layer-3 BN2+ReLU fused into A-staging for K in [896,1152) from raw aggb
  k_mgemm<128, 64, 3><<<dim3(1, MPAD/128), 128, 0, stream>>>(
      (const bf16*)xcat, (const bf16*)whead, out, ball, nullptr,
      sums8 + 7*512, bn2g + 3*HID, bn2b + 3*HID, (const bf16*)aggb,
      N_NODES, OUT_DIM, KCAT, invM);
}

// Round 10
// 549.991 us; speedup vs baseline: 1.2910x; 1.2309x over previous
//
#include <hip/hip_runtime.h>

#define N_NODES 50000
#define MPAD    50176
#define N_EDGES 800000
#define IN_DIM 128
#define HID 256
#define OUT_DIM 64
#define N_CONV 4
#define KCAT 1152   // 128 + 4*256
#define NREP 8      // stat-replica count (contention /8)

typedef __bf16 bf16;
typedef __attribute__((ext_vector_type(8))) __bf16 bf16x8;
typedef __attribute__((ext_vector_type(4))) float f32x4;
typedef unsigned short ushort_t;

__device__ __forceinline__ unsigned short f2b(float f){
  unsigned u = __float_as_uint(f);
  u += 0x7fffu + ((u >> 16) & 1u);
  return (unsigned short)(u >> 16);
}
__device__ __forceinline__ float b2f_lo(unsigned v){ return __uint_as_float(v << 16); }
__device__ __forceinline__ float b2f_hi(unsigned v){ return __uint_as_float(v & 0xffff0000u); }

__device__ __forceinline__ void stage16(const void* g, void* l){
  __builtin_amdgcn_global_load_lds((const __attribute__((address_space(1))) unsigned int*)g,
                                   (__attribute__((address_space(3))) unsigned int*)l, 16, 0, 0);
}

// ---------------- CSR build ----------------
__global__ void k_count(const int* __restrict__ dst, int* __restrict__ cnt, int ne){
  int e = blockIdx.x*blockDim.x + threadIdx.x;
  if (e < ne) atomicAdd(&cnt[dst[e]], 1);
}

__global__ void k_scan1(const int* __restrict__ cnt, int* __restrict__ scanned,
                        int* __restrict__ bsum, int n){
  int i = blockIdx.x*256 + threadIdx.x;
  int v = (i < n) ? cnt[i] : 0;
  int lane = threadIdx.x & 63;
  #pragma unroll
  for (int off = 1; off < 64; off <<= 1){
    int t = __shfl_up(v, off, 64);
    if (lane >= off) v += t;
  }
  __shared__ int wsum[4];
  int wv = threadIdx.x >> 6;
  if (lane == 63) wsum[wv] = v;
  __syncthreads();
  if (threadIdx.x == 0){
    int s = 0;
    #pragma unroll
    for (int k = 0; k < 4; ++k){ int t = wsum[k]; wsum[k] = s; s += t; }
    bsum[blockIdx.x] = s;
  }
  __syncthreads();
  v += wsum[wv];
  if (i < n) scanned[i] = v;
}

__global__ void k_scan2(int* __restrict__ bsum, int nb){
  __shared__ int sd[256];
  int i = threadIdx.x;
  sd[i] = (i < nb) ? bsum[i] : 0;
  __syncthreads();
  #pragma unroll
  for (int off = 1; off < 256; off <<= 1){
    int t = (i >= off) ? sd[i-off] : 0;
    __syncthreads();
    sd[i] += t;
    __syncthreads();
  }
  if (i < nb) bsum[i] = sd[i];
}

__global__ void k_scan3(const int* __restrict__ scanned, const int* __restrict__ bsum,
                        const int* __restrict__ cnt, int* __restrict__ row_ptr,
                        int* __restrict__ cursor, int n){
  int i = blockIdx.x*256 + threadIdx.x;
  if (i < n){
    int off = (blockIdx.x > 0) ? bsum[blockIdx.x-1] : 0;
    int inc = scanned[i] + off;
    row_ptr[i+1] = inc;
    cursor[i] = inc - cnt[i];
  }
  if (i == 0) row_ptr[0] = 0;
}

__global__ void k_fill(const int* __restrict__ src, const int* __restrict__ dst,
                       int* __restrict__ cursor, int* __restrict__ esrc, int ne){
  int e = blockIdx.x*blockDim.x + threadIdx.x;
  if (e < ne){
    int p = atomicAdd(&cursor[dst[e]], 1);
    esrc[p] = src[e];
  }
}

// ---------------- zero helper: 4 byte-ranges in one dispatch ----------------
__global__ void k_zero(char* p0, int n0, char* p1, int n1, char* p2, int n2, char* p3, int n3){
  int i = (blockIdx.x*blockDim.x + threadIdx.x) * 16;
  if (i < n0) *(uint4*)(p0 + i) = make_uint4(0,0,0,0);
  i -= n0;
  if (i >= 0 && i < n1) *(uint4*)(p1 + i) = make_uint4(0,0,0,0);
  i -= n1;
  if (i >= 0 && i < n2) *(uint4*)(p2 + i) = make_uint4(0,0,0,0);
  i -= n2;
  if (i >= 0 && i < n3) *(uint4*)(p3 + i) = make_uint4(0,0,0,0);
}

// ---------------- aggregation from xcat slice (bf16, fp32 accum, 8x MLP) ----------------
template<int D>
__global__ void k_agg(const ushort_t* __restrict__ x, const int* __restrict__ rp,
                      const int* __restrict__ es, ushort_t* __restrict__ agg, int n){
  int gw = (int)((blockIdx.x*(size_t)blockDim.x + threadIdx.x) >> 6);
  int lane = threadIdx.x & 63;
  if (gw >= n) return;
  if (D == 256){
    const uint2* xp = (const uint2*)x; const int S = KCAT/4;
    uint2 v = xp[(size_t)gw*S + lane];
    float a0=b2f_lo(v.x), a1=b2f_hi(v.x), a2=b2f_lo(v.y), a3=b2f_hi(v.y);
    float c0=0.f, c1=0.f, c2=0.f, c3=0.f;
    int e = rp[gw], e1 = rp[gw+1];
    for (; e + 8 <= e1; e += 8){
      uint2 w[8];
      #pragma unroll
      for (int u = 0; u < 8; ++u) w[u] = xp[(size_t)es[e+u]*S + lane];
      #pragma unroll
      for (int u = 0; u < 8; u += 2){
        a0 += b2f_lo(w[u].x);   a1 += b2f_hi(w[u].x);   a2 += b2f_lo(w[u].y);   a3 += b2f_hi(w[u].y);
        c0 += b2f_lo(w[u+1].x); c1 += b2f_hi(w[u+1].x); c2 += b2f_lo(w[u+1].y); c3 += b2f_hi(w[u+1].y);
      }
    }
    for (; e + 2 <= e1; e += 2){
      uint2 w0 = xp[(size_t)es[e]*S + lane];
      uint2 w1 = xp[(size_t)es[e+1]*S + lane];
      a0 += b2f_lo(w0.x); a1 += b2f_hi(w0.x); a2 += b2f_lo(w0.y); a3 += b2f_hi(w0.y);
      c0 += b2f_lo(w1.x); c1 += b2f_hi(w1.x); c2 += b2f_lo(w1.y); c3 += b2f_hi(w1.y);
    }
    if (e < e1){
      uint2 w0 = xp[(size_t)es[e]*S + lane];
      a0 += b2f_lo(w0.x); a1 += b2f_hi(w0.x); a2 += b2f_lo(w0.y); a3 += b2f_hi(w0.y);
    }
    a0 += c0; a1 += c1; a2 += c2; a3 += c3;
    unsigned o0 = (unsigned)f2b(a0) | ((unsigned)f2b(a1) << 16);
    unsigned o1 = (unsigned)f2b(a2) | ((unsigned)f2b(a3) << 16);
    *(uint2*)(agg + (size_t)gw*256 + lane*4) = make_uint2(o0, o1);
  } else {
    const unsigned* xp = (const unsigned*)x; const int S = KCAT/2;
    unsigned v = xp[(size_t)gw*S + lane];
    float a0 = b2f_lo(v), a1 = b2f_hi(v);
    float c0 = 0.f, c1 = 0.f;
    int e = rp[gw], e1 = rp[gw+1];
    for (; e + 8 <= e1; e += 8){
      unsigned w[8];
      #pragma unroll
      for (int u = 0; u < 8; ++u) w[u] = xp[(size_t)es[e+u]*S + lane];
      #pragma unroll
      for (int u = 0; u < 8; u += 2){
        a0 += b2f_lo(w[u]);   a1 += b2f_hi(w[u]);
        c0 += b2f_lo(w[u+1]); c1 += b2f_hi(w[u+1]);
      }
    }
    for (; e + 2 <= e1; e += 2){
      unsigned w0 = xp[(size_t)es[e]*S + lane];
      unsigned w1 = xp[(size_t)es[e+1]*S + lane];
      a0 += b2f_lo(w0); a1 += b2f_hi(w0);
      c0 += b2f_lo(w1); c1 += b2f_hi(w1);
    }
    if (e < e1){
      unsigned w0 = xp[(size_t)es[e]*S + lane];
      a0 += b2f_lo(w0); a1 += b2f_hi(w0);
    }
    a0 += c0; a1 += c1;
    unsigned o = (unsigned)f2b(a0) | ((unsigned)f2b(a1) << 16);
    *(unsigned*)(agg + (size_t)gw*128 + lane*2) = o;
  }
}

// ---------------- BN+ReLU (bf16 in/out, stats from NREP replicas, grid-stride) ----------------
__global__ __launch_bounds__(256) void k_bnrelu(const ushort_t* __restrict__ t,
                         const float* __restrict__ sums,
                         const float* __restrict__ g, const float* __restrict__ b,
                         ushort_t* __restrict__ o, int ostride, int M, float invM){
  __shared__ float sc[256], sh[256];
  {
    int c = threadIdx.x;
    float s1 = 0.f, s2 = 0.f;
    #pragma unroll
    for (int rp = 0; rp < NREP; ++rp){
      s1 += sums[(rp<<9) + c];
      s2 += sums[(rp<<9) + 256 + c];
    }
    float m = s1 * invM;
    float var = s2 * invM - m*m;
    float rs = rsqrtf(var + 1e-5f);
    float s = rs * g[c];
    sc[c] = s;
    sh[c] = b[c] - m*s;
  }
  __syncthreads();
  const int total = M*(HID/8);
  for (int idx = blockIdx.x*256 + threadIdx.x; idx < total; idx += gridDim.x*256){
    int row = idx >> 5, cg = (idx & 31) * 8;
    uint4 v = *(const uint4*)(t + (size_t)row*HID + cg);
    unsigned wv[4] = {v.x, v.y, v.z, v.w};
    unsigned ov[4];
    #pragma unroll
    for (int p = 0; p < 4; ++p){
      int c0 = cg + 2*p, c1 = c0 + 1;
      float y0 = fmaf(b2f_lo(wv[p]), sc[c0], sh[c0]);
      float y1 = fmaf(b2f_hi(wv[p]), sc[c1], sh[c1]);
      y0 = y0 > 0.f ? y0 : 0.f; y1 = y1 > 0.f ? y1 : 0.f;
      ov[p] = (unsigned)f2b(y0) | ((unsigned)f2b(y1) << 16);
    }
    *(uint4*)(o + (size_t)row*ostride + cg) = make_uint4(ov[0], ov[1], ov[2], ov[3]);
  }
}

// ---------------- h fp32 -> bf16 into xcat col 0..127 ----------------
__global__ void k_f2b(const float* __restrict__ in, ushort_t* __restrict__ xcat, int n8){
  int idx = blockIdx.x*blockDim.x + threadIdx.x;
  if (idx >= n8) return;
  int row = idx >> 4, cg = (idx & 15) * 8;
  float4 a = *(const float4*)(in + (size_t)row*IN_DIM + cg);
  float4 c = *(const float4*)(in + (size_t)row*IN_DIM + cg + 4);
  unsigned o0 = (unsigned)f2b(a.x) | ((unsigned)f2b(a.y) << 16);
  unsigned o1 = (unsigned)f2b(a.z) | ((unsigned)f2b(a.w) << 16);
  unsigned o2 = (unsigned)f2b(c.x) | ((unsigned)f2b(c.y) << 16);
  unsigned o3 = (unsigned)f2b(c.z) | ((unsigned)f2b(c.w) << 16);
  *(uint4*)(xcat + (size_t)row*KCAT + cg) = make_uint4(o0, o1, o2, o3);
}

// ---------------- weight transpose + convert (+ fused bias fold) ----------------
__global__ void k_wprep(const float* __restrict__ c0W1, const float* __restrict__ cW1,
                        const float* __restrict__ cW2, const float* __restrict__ p0W,
                        const float* __restrict__ pW,
                        const float* __restrict__ p0b, const float* __restrict__ pb,
                        ushort_t* __restrict__ wb, ushort_t* __restrict__ whead,
                        float* __restrict__ ball){
  int m = blockIdx.y;
  if (m == 13){
    if (blockIdx.x == 0 && threadIdx.x < OUT_DIM){
      int c = threadIdx.x;
      float v = p0b[c];
      #pragma unroll
      for (int i = 0; i < N_CONV; ++i) v += pb[i*OUT_DIM + c];
      ball[c] = v;
    }
    return;
  }
  const float* src; int R, C; ushort_t* dst; int dstride, dcol;
  if (m == 0){       src = c0W1;              R = 128; C = 256; dst = wb;                       dstride = 128;  dcol = 0; }
  else if (m <= 3){  src = cW1 + (m-1)*65536; R = 256; C = 256; dst = wb + 32768 + (m-1)*65536; dstride = 256;  dcol = 0; }
  else if (m <= 7){  src = cW2 + (m-4)*65536; R = 256; C = 256; dst = wb + 229376 + (m-4)*65536;dstride = 256;  dcol = 0; }
  else if (m == 8){  src = p0W;               R = 128; C = 64;  dst = whead;                    dstride = KCAT; dcol = 0; }
  else {             src = pW + (m-9)*16384;  R = 256; C = 64;  dst = whead;                    dstride = KCAT; dcol = 128 + (m-9)*256; }
  int tx = R/64, tiles = tx * (C/64);
  int t = blockIdx.x;
  if (t >= tiles) return;
  int sr0 = (t % tx)*64, sc0 = (t / tx)*64;
  __shared__ float ld[64][65];
  int c = threadIdx.x & 63, rq = threadIdx.x >> 6;
  #pragma unroll
  for (int i = 0; i < 16; ++i){
    int rr = i*4 + rq;
    ld[rr][c] = src[(size_t)(sr0+rr)*C + sc0 + c];
  }
  __syncthreads();
  #pragma unroll
  for (int i = 0; i < 16; ++i){
    int rr = i*4 + rq;
    dst[(size_t)(sc0+rr)*dstride + dcol + sr0 + c] = f2b(ld[c][rr]);
  }
}

// ---------------- MFMA GEMM: C[M,N] = A[M,K](bf16) @ BT[N,K](bf16)^T ----------------
// Double-buffered LDS (A and B via global_load_lds), one barrier per K-tile.
// MODE 0: round acc->bf16, fused column stats (NREP-replicated atomics), bf16 C
// MODE 1: fp32 C + bias[col], masked row<M
// MODE 2: like MODE 0, A reg-staged with fused BN(asums-replicas)+ReLU affine, pad zeroing
// MODE 3: like MODE 1, A hybrid: k<896 stage16 from A; k>=896 reg-staged from A2 with BN+ReLU
template<int BM, int BN, int MODE>
__global__ __launch_bounds__((BM/64)*(BN/64)*64)
void k_mgemm(const bf16* __restrict__ A, const bf16* __restrict__ BT,
             void* __restrict__ Cv, const float* __restrict__ bias,
             float* __restrict__ sums, const float* __restrict__ asums,
             const float* __restrict__ ag, const float* __restrict__ ab,
             const bf16* __restrict__ A2,
             int M, int N, int K, float invM)
{
  constexpr int NW  = (BM/64)*(BN/64);
  constexpr int WNT = BN/64;
  constexpr int ACH = BM/16, BCH = BN/16;
  __shared__ __align__(16) bf16 As[2*BM*32];
  __shared__ __align__(16) bf16 Bs[2*BN*32];
  __shared__ float sAf[(MODE>=2)?256:1];
  __shared__ float tAf[(MODE>=2)?256:1];
  const int tid = threadIdx.x;
  const int wid = tid >> 6, l = tid & 63;
  const int wm = wid / WNT, wn = wid % WNT;
  const int m0 = blockIdx.y * BM, n0 = blockIdx.x * BN;
  const int r = l & 15, q = l >> 4;
  const int fragByte = ((q ^ ((r >> 1) & 3)) << 4);
  const int wrow = l >> 2;
  const int wk = (((l & 3) ^ ((l >> 3) & 3)) << 3);

  if constexpr (MODE >= 2){
    for (int c = tid; c < 256; c += NW*64){
      float s1 = 0.f, s2 = 0.f;
      #pragma unroll
      for (int rp = 0; rp < NREP; ++rp){
        s1 += asums[(rp<<9) + c];
        s2 += asums[(rp<<9) + 256 + c];
      }
      float m = s1 * invM;
      float var = s2 * invM - m*m;
      float s = rsqrtf(var + 1e-5f) * ag[c];
      sAf[c] = s;
      tAf[c] = ab[c] - m*s;
    }
    __syncthreads();
  }

  auto REGSTAGE_A = [&](int buf, int ch, const bf16* srcRow, int kc){
    uint4 raw = *(const uint4*)(srcRow);
    unsigned rv[4] = {raw.x, raw.y, raw.z, raw.w};
    unsigned ov[4];
    #pragma unroll
    for (int p = 0; p < 4; ++p){
      int c0 = kc + 2*p, c1 = c0 + 1;
      float y0 = fmaf(b2f_lo(rv[p]), sAf[c0], tAf[c0]);
      float y1 = fmaf(b2f_hi(rv[p]), sAf[c1], tAf[c1]);
      y0 = y0 > 0.f ? y0 : 0.f; y1 = y1 > 0.f ? y1 : 0.f;
      ov[p] = (unsigned)f2b(y0) | ((unsigned)f2b(y1) << 16);
    }
    int grow = m0 + ch*16 + wrow;
    if (grow >= M){ ov[0]=0; ov[1]=0; ov[2]=0; ov[3]=0; }
    *(uint4*)((char*)As + buf*(BM*64) + ch*1024 + l*16) = make_uint4(ov[0],ov[1],ov[2],ov[3]);
  };

  auto STAGE = [&](int buf, int k0){
    #pragma unroll
    for (int c = 0; c < ACH/NW; ++c){
      int ch = wid + c*NW;
      int grow = m0 + ch*16 + wrow;
      if constexpr (MODE == 2){
        REGSTAGE_A(buf, ch, A + (size_t)grow*K + (k0 + wk), k0 + wk);
      } else if constexpr (MODE == 3){
        if (k0 < 896){
          const bf16* g = A + (size_t)grow*K + (k0 + wk);
          stage16(g, (char*)As + buf*(BM*64) + ch*1024);
        } else {
          int kc = k0 - 896 + wk;
          REGSTAGE_A(buf, ch, A2 + (size_t)grow*HID + kc, kc);
        }
      } else {
        const bf16* g = A + (size_t)grow*K + (k0 + wk);
        stage16(g, (char*)As + buf*(BM*64) + ch*1024);
      }
    }
    #pragma unroll
    for (int c = 0; c < BCH/NW; ++c){
      int ch = wid + c*NW;
      const bf16* g = BT + (size_t)(n0 + ch*16 + wrow)*K + (k0 + wk);
      stage16(g, (char*)Bs + buf*(BN*64) + ch*1024);
    }
  };

  f32x4 acc[4][4] = {};
  const int nt = K >> 5;
  STAGE(0, 0);
  for (int t = 0; t < nt; ++t){
    int cur = t & 1;
    __syncthreads();
    if (t + 1 < nt) STAGE(cur ^ 1, (t + 1) << 5);
    bf16x8 af[4], bfr[4];
    #pragma unroll
    for (int mf = 0; mf < 4; ++mf)
      af[mf] = *(const bf16x8*)((const char*)As + cur*(BM*64) + (wm*64 + mf*16 + r)*64 + fragByte);
    #pragma unroll
    for (int nf = 0; nf < 4; ++nf)
      bfr[nf] = *(const bf16x8*)((const char*)Bs + cur*(BN*64) + (wn*64 + nf*16 + r)*64 + fragByte);
    #pragma unroll
    for (int mf = 0; mf < 4; ++mf)
      #pragma unroll
      for (int nf = 0; nf < 4; ++nf)
        acc[mf][nf] = __builtin_amdgcn_mfma_f32_16x16x32_bf16(af[mf], bfr[nf], acc[mf][nf], 0, 0, 0);
  }

  if (MODE == 0 || MODE == 2){
    ushort_t* Cb = (ushort_t*)Cv;
    float s1[4] = {0.f,0.f,0.f,0.f}, s2[4] = {0.f,0.f,0.f,0.f};
    #pragma unroll
    for (int mf = 0; mf < 4; ++mf){
      #pragma unroll
      for (int j = 0; j < 4; ++j){
        int row = m0 + wm*64 + mf*16 + q*4 + j;
        #pragma unroll
        for (int nf = 0; nf < 4; ++nf){
          unsigned short us = f2b(acc[mf][nf][j]);
          float vr = __uint_as_float((unsigned)us << 16);
          s1[nf] += vr; s2[nf] = fmaf(vr, vr, s2[nf]);
          Cb[(size_t)row*N + n0 + wn*64 + nf*16 + r] = us;
        }
      }
    }
    float* sr = sums + ((blockIdx.y & (NREP-1)) << 9);
    #pragma unroll
    for (int nf = 0; nf < 4; ++nf){
      float a = s1[nf], c = s2[nf];
      a += __shfl_xor(a, 16, 64); a += __shfl_xor(a, 32, 64);
      c += __shfl_xor(c, 16, 64); c += __shfl_xor(c, 32, 64);
      if (q == 0){
        int col = n0 + wn*64 + nf*16 + r;
        atomicAdd(&sr[col], a);
        atomicAdd(&sr[256 + col], c);
      }
    }
  } else {
    float* C = (float*)Cv;
    #pragma unroll
    for (int mf = 0; mf < 4; ++mf){
      #pragma unroll
      for (int j = 0; j < 4; ++j){
        int row = m0 + wm*64 + mf*16 + q*4 + j;
        if (row >= M) continue;
        #pragma unroll
        for (int nf = 0; nf < 4; ++nf){
          int col = n0 + wn*64 + nf*16 + r;
          C[(size_t)row*N + col] = acc[mf][nf][j] + bias[col];
        }
      }
    }
  }
}

extern "C" void kernel_launch(void* const* d_in, const int* in_sizes, int n_in,
                              void* d_out, int out_size, void* d_ws, size_t ws_size,
                              hipStream_t stream){
  const float* h    = (const float*)d_in[0];
  const float* c0W1 = (const float*)d_in[1];
  const float* cW1  = (const float*)d_in[2];
  const float* cW2  = (const float*)d_in[3];
  const float* bn1g = (const float*)d_in[4];
  const float* bn1b = (const float*)d_in[5];
  const float* bn2g = (const float*)d_in[6];
  const float* bn2b = (const float*)d_in[7];
  const float* p0W  = (const float*)d_in[8];
  const float* p0b  = (const float*)d_in[9];
  const float* pW   = (const float*)d_in[10];
  const float* pb   = (const float*)d_in[11];
  const int* src    = (const int*)d_in[12];
  const int* dst    = (const int*)d_in[13];
  float* out = (float*)d_out;

  char* w = (char*)d_ws;
  auto alloc = [&](size_t bytes)->char*{ char* p = w; w += (bytes + 255) & ~(size_t)255; return p; };
  ushort_t* xcat = (ushort_t*)alloc((size_t)MPAD*KCAT*2);
  ushort_t* aggb = (ushort_t*)alloc((size_t)MPAD*HID*2);
  ushort_t* tt   = (ushort_t*)alloc((size_t)MPAD*HID*2);
  ushort_t* wb   = (ushort_t*)alloc((size_t)491520*2);
  ushort_t* whead= (ushort_t*)alloc((size_t)OUT_DIM*KCAT*2);
  int* row_ptr   = (int*)alloc((N_NODES+1)*4);
  int* cursor    = (int*)alloc(N_NODES*4);
  int* counts    = (int*)alloc(N_NODES*4);
  int* esrc      = (int*)alloc(N_EDGES*4);
  int* scanned   = (int*)alloc(N_NODES*4);
  int* bsum      = (int*)alloc(256*4);
  float* sums8   = (float*)alloc(8*NREP*512*4);   // 8 GEMM slots x NREP replicas x 512
  float* ball    = (float*)alloc(OUT_DIM*4);

  // pad-row zeroing (aggb 128-wide + 256-wide views) + replicated sums + counts
  {
    const int PADR = MPAD - N_NODES;
    int n0 = PADR*IN_DIM*2, n1 = PADR*HID*2, n2 = 8*NREP*512*4, n3 = N_NODES*4;
    int chunks = (n0 + n1 + n2 + n3) / 16;
    k_zero<<<(chunks + 255)/256, 256, 0, stream>>>(
        (char*)(aggb + (size_t)N_NODES*IN_DIM), n0,
        (char*)(aggb + (size_t)N_NODES*HID), n1,
        (char*)sums8, n2, (char*)counts, n3);
  }

  // ---- CSR build (by dst) ----
  const int NB = (N_NODES + 255) / 256;
  k_count<<<(N_EDGES+255)/256, 256, 0, stream>>>(dst, counts, N_EDGES);
  k_scan1<<<NB, 256, 0, stream>>>(counts, scanned, bsum, N_NODES);
  k_scan2<<<1, 256, 0, stream>>>(bsum, NB);
  k_scan3<<<NB, 256, 0, stream>>>(scanned, bsum, counts, row_ptr, cursor, N_NODES);
  k_fill<<<(N_EDGES+255)/256, 256, 0, stream>>>(src, dst, cursor, esrc, N_EDGES);

  // ---- weight prep (+bias fold) + h->xcat ----
  k_wprep<<<dim3(16, 14), 256, 0, stream>>>(c0W1, cW1, cW2, p0W, pW, p0b, pb, wb, whead, ball);
  k_f2b<<<(N_NODES*16 + 255)/256, 256, 0, stream>>>(h, xcat, N_NODES*16);

  const float invM = 1.0f / (float)N_NODES;
  for (int i = 0; i < N_CONV; ++i){
    int K1 = (i == 0) ? IN_DIM : HID;
    const ushort_t* xin = (i == 0) ? xcat : (xcat + 128 + (size_t)(i-1)*HID);
    if (i == 0)
      k_agg<IN_DIM><<<(N_NODES*64+255)/256, 256, 0, stream>>>(xin, row_ptr, esrc, aggb, N_NODES);
    else
      k_agg<HID><<<(N_NODES*64+255)/256, 256, 0, stream>>>(xin, row_ptr, esrc, aggb, N_NODES);

    float* sums1 = sums8 + (size_t)(2*i)*NREP*512;
    float* sums2 = sums8 + (size_t)(2*i+1)*NREP*512;

    // GEMM1: tt = aggb @ W1  (+ fused replicated stats of rounded output)
    const ushort_t* W1T = (i == 0) ? wb : (wb + 32768 + (size_t)(i-1)*65536);
    k_mgemm<64, 256, 0><<<dim3(1, MPAD/64), 256, 0, stream>>>(
        (const bf16*)aggb, (const bf16*)W1T, tt, nullptr, sums1,
        nullptr, nullptr, nullptr, nullptr, N_NODES, HID, K1, invM);

    // GEMM2: aggb = relu(bn1(tt)) @ W2  (BN1+ReLU fused into A-staging; replicated stats)
    const ushort_t* W2T = wb + 229376 + (size_t)i*65536;
    k_mgemm<64, 256, 2><<<dim3(1, MPAD/64), 256, 0, stream>>>(
        (const bf16*)tt, (const bf16*)W2T, aggb, nullptr, sums2,
        sums1, bn1g + i*HID, bn1b + i*HID, nullptr, N_NODES, HID, HID, invM);

    // BN2+ReLU -> xcat slice (layers 0..2; layer 3 fused into head GEMM)
    if (i < 3)
      k_bnrelu<<<1024, 256, 0, stream>>>(
          aggb, sums2, bn2g + i*HID, bn2b + i*HID, xcat + 128 + (size_t)i*HID, KCAT, N_NODES, invM);
  }

  // ---- consolidated jumping-knowledge head GEMM: out = xcat @ whead^T + ball ----
  // layer-3 BN2+ReLU fused into A-staging for K in [896,1152) from raw aggb
  k_mgemm<128, 64, 3><<<dim3(1, MPAD/128), 128, 0, stream>>>(
      (const bf16*)xcat, (const bf16*)whead, out, ball, nullptr,
      sums8 + (size_t)7*NREP*512, bn2g + 3*HID, bn2b + 3*HID, (const bf16*)aggb,
      N_NODES, OUT_DIM, KCAT, invM);
}